// Round 1
// baseline (277.708 us; speedup 1.0000x reference)
//
#include <hip/hip_runtime.h>

#define DM 1024
#define NHEAD 16
#define DK 64

typedef short bf16x8 __attribute__((ext_vector_type(8)));
typedef float f32x4 __attribute__((ext_vector_type(4)));

__device__ __forceinline__ unsigned short f2bf(float f) {
  union { float f; unsigned u; } v; v.f = f;
  return (unsigned short)((v.u + 0x7fffu + ((v.u >> 16) & 1u)) >> 16);
}

__device__ __forceinline__ void gld16(const void* g, void* l) {
  __builtin_amdgcn_global_load_lds((const __attribute__((address_space(1))) void*)g,
                                   (__attribute__((address_space(3))) void*)l, 16, 0, 0);
}

// ---------------- elementwise prep ----------------
__global__ void k_conv(const float* __restrict__ src, unsigned short* __restrict__ dst,
                       int n, float scale) {
  int i = (blockIdx.x * blockDim.x + threadIdx.x) * 4;
  if (i >= n) return;
  float4 v = *(const float4*)(src + i);
  ushort4 o;
  o.x = f2bf(v.x * scale); o.y = f2bf(v.y * scale);
  o.z = f2bf(v.z * scale); o.w = f2bf(v.w * scale);
  *(ushort4*)(dst + i) = o;
}

__global__ void k_scale_f32(const float* __restrict__ src, float* __restrict__ dst,
                            int n, float s) {
  int i = blockIdx.x * blockDim.x + threadIdx.x;
  if (i < n) dst[i] = src[i] * s;
}

__global__ void k_ltw(const float* __restrict__ coords, float* __restrict__ ltw, int S) {
  int s = blockIdx.x * blockDim.x + threadIdx.x;
  if (s >= S) return;
  float a = (s > 0)     ? fabsf(coords[s] - coords[s - 1]) : 0.f;
  float b = (s < S - 1) ? fabsf(coords[s + 1] - coords[s]) : 0.f;
  float tw = 0.5f * (a + b);
  ltw[s] = (tw > 0.f) ? logf(tw) : -1e30f;
}

// ---------------- GEMM: C[M,N] = A[M,K] * B[N,K]^T + bias ----------------
// A,B bf16 row-major ([M][K], [N][K]); OUTF32 ? C f32 : C bf16.
#define BM 128
#define BN 128
#define BKK 64

template<int OUTF32>
__global__ __launch_bounds__(256)
void gemm_bt(const unsigned short* __restrict__ A, const unsigned short* __restrict__ B,
             const float* __restrict__ bias, void* __restrict__ C,
             int M, int N, int K) {
  __shared__ __align__(16) unsigned short sA[2][BM * BKK];
  __shared__ __align__(16) unsigned short sB[2][BN * BKK];
  const int tid = threadIdx.x;
  const int lane = tid & 63;
  const int wid = tid >> 6;
  const int rr = lane & 15, g = lane >> 4;
  const int nbn = N / BN;
  const int bm = blockIdx.x / nbn, bn = blockIdx.x % nbn;
  const int wr = wid >> 1, wc = wid & 1;
  const int nkt = K / BKK;

  const unsigned short* Abase = A + (size_t)bm * BM * K;
  const unsigned short* Bbase = B + (size_t)bn * BN * K;

  auto stage = [&](int buf, int kt) {
#pragma unroll
    for (int j = 0; j < 4; ++j) {
      int o = j * 256 + tid;        // 16B chunk index, 1024 per tile
      int row = o >> 3;
      int ce = (o & 7) * 8;         // element col
      gld16(Abase + (size_t)row * K + kt * BKK + ce, &sA[buf][o * 8]);
      gld16(Bbase + (size_t)row * K + kt * BKK + ce, &sB[buf][o * 8]);
    }
  };

  f32x4 acc[4][4] = {};
  stage(0, 0);
  int cur = 0;
  for (int kt = 0; kt < nkt; ++kt) {
    __syncthreads();                       // staged tile ready; prior reads drained
    if (kt + 1 < nkt) stage(cur ^ 1, kt + 1);
    const unsigned short* a0 = &sA[cur][(wr * 64) * BKK];
    const unsigned short* b0 = &sB[cur][(wc * 64) * BKK];
#pragma unroll
    for (int kk = 0; kk < 2; ++kk) {
      const int co = kk * 32 + g * 8;
      bf16x8 af[4], bfr[4];
#pragma unroll
      for (int m = 0; m < 4; ++m)
        af[m] = *(const bf16x8*)&a0[(m * 16 + rr) * BKK + co];
#pragma unroll
      for (int n = 0; n < 4; ++n)
        bfr[n] = *(const bf16x8*)&b0[(n * 16 + rr) * BKK + co];
#pragma unroll
      for (int m = 0; m < 4; ++m)
#pragma unroll
        for (int n = 0; n < 4; ++n)
          acc[m][n] = __builtin_amdgcn_mfma_f32_16x16x32_bf16(af[m], bfr[n], acc[m][n], 0, 0, 0);
    }
    cur ^= 1;
  }

  const int crow0 = bm * BM + wr * 64;
  const int ccol0 = bn * BN + wc * 64;
#pragma unroll
  for (int n = 0; n < 4; ++n) {
    const int col = ccol0 + n * 16 + rr;
    const float bn_ = bias ? bias[col] : 0.f;
#pragma unroll
    for (int m = 0; m < 4; ++m)
#pragma unroll
      for (int r = 0; r < 4; ++r) {
        const int row = crow0 + m * 16 + g * 4 + r;
        float v = acc[m][n][r] + bn_;
        if (OUTF32) ((float*)C)[(size_t)row * N + col] = v;
        else ((unsigned short*)C)[(size_t)row * N + col] = f2bf(v);
      }
  }
}

// ---------------- V transpose: V[B][S][DM] -> Vt[B*H][DK][S] ----------------
__global__ __launch_bounds__(256)
void k_transpose(const unsigned short* __restrict__ V, unsigned short* __restrict__ Vt, int S) {
  __shared__ __align__(16) unsigned short t[64][72];
  const int nst = S / 64;
  int bidx = blockIdx.x;
  int st = bidx % nst;
  int bh = bidx / nst;           // b*NHEAD + h
  int h = bh & (NHEAD - 1), b = bh / NHEAD;
  const unsigned short* src = V + ((size_t)b * S + st * 64) * DM + h * DK;
  unsigned short* dst = Vt + (size_t)bh * DK * S + st * 64;
  int tid = threadIdx.x;
#pragma unroll
  for (int i = 0; i < 2; ++i) {
    int r = i * 32 + (tid >> 3);
    int c = (tid & 7) * 8;
    *(uint4*)&t[r][c] = *(const uint4*)&src[(size_t)r * DM + c];
  }
  __syncthreads();
#pragma unroll
  for (int i = 0; i < 2; ++i) {
    int d = i * 32 + (tid >> 3);
    int s = (tid & 7) * 8;
    unsigned short tmp[8];
#pragma unroll
    for (int j = 0; j < 8; ++j) tmp[j] = t[s + j][d];
    *(uint4*)&dst[(size_t)d * S + s] = *(const uint4*)&tmp[0];
  }
}

// ---------------- flash attention with log-trapezoid bias ----------------
// Q,K: [B][S][DM] bf16; Vt: [B*H][DK][S] bf16; O: [B][S][DM] bf16.
__global__ __launch_bounds__(256)
void k_attn(const unsigned short* __restrict__ Q, const unsigned short* __restrict__ K,
            const unsigned short* __restrict__ Vt, const float* __restrict__ ltw,
            unsigned short* __restrict__ O, int S) {
  __shared__ __align__(16) unsigned short sK[2][64 * 64];
  __shared__ __align__(16) unsigned short sV[2][64 * 64];
  __shared__ __align__(16) unsigned short sP[4][16 * 72];
  const int tid = threadIdx.x, lane = tid & 63, wid = tid >> 6;
  const int rr = lane & 15, g = lane >> 4;
  const int nqt = S / 64;
  const int qt = blockIdx.x % nqt;
  const int bh = blockIdx.x / nqt;
  const int h = bh & (NHEAD - 1), b = bh / NHEAD;

  const unsigned short* Qbase = Q + ((size_t)b * S + qt * 64 + wid * 16) * DM + h * DK;
  const unsigned short* Kbase = K + (size_t)b * S * DM + h * DK;
  const unsigned short* Vbase = Vt + (size_t)bh * DK * S;

  bf16x8 aq[2];
  aq[0] = *(const bf16x8*)&Qbase[(size_t)rr * DM + g * 8];
  aq[1] = *(const bf16x8*)&Qbase[(size_t)rr * DM + 32 + g * 8];

  f32x4 acc[4] = {};
  float mrow[4], lrow[4];
#pragma unroll
  for (int r = 0; r < 4; ++r) { mrow[r] = -1e30f; lrow[r] = 0.f; }

  auto stage = [&](int buf, int kt) {
#pragma unroll
    for (int j = 0; j < 2; ++j) {
      int o = j * 256 + tid;       // 512 chunks of 16B per tile
      int row = o >> 3;
      int cb = ((o & 7) * 16) ^ ((row & 7) << 4);   // inverse-swizzled source byte col
      gld16((const char*)(Kbase + (size_t)(kt * 64 + row) * DM) + cb, &sK[buf][o * 8]);
      gld16((const char*)(Vbase + (size_t)row * S + kt * 64) + cb, &sV[buf][o * 8]);
    }
  };

  stage(0, 0);
  int cur = 0;
  const int nkt = S / 64;
  for (int kt = 0; kt < nkt; ++kt) {
    __syncthreads();
    if (kt + 1 < nkt) stage(cur ^ 1, kt + 1);

    // scores: S[16q][64k] as 4 frags of 16x16, K=64 via 2 MFMAs each
    f32x4 s[4];
#pragma unroll
    for (int f = 0; f < 4; ++f) {
      const int row = f * 16 + rr;
      const int swz = (row & 7) << 4;
      bf16x8 k0 = *(const bf16x8*)((const char*)&sK[cur][row * 64] + ((g * 16) ^ swz));
      bf16x8 k1 = *(const bf16x8*)((const char*)&sK[cur][row * 64] + ((64 + g * 16) ^ swz));
      f32x4 z = {};
      z = __builtin_amdgcn_mfma_f32_16x16x32_bf16(aq[0], k0, z, 0, 0, 0);
      s[f] = __builtin_amdgcn_mfma_f32_16x16x32_bf16(aq[1], k1, z, 0, 0, 0);
    }
    // + log trapezoid weight (per key = per col = rr + f*16)
    float lt[4];
#pragma unroll
    for (int f = 0; f < 4; ++f) lt[f] = ltw[kt * 64 + f * 16 + rr];
#pragma unroll
    for (int f = 0; f < 4; ++f)
#pragma unroll
      for (int r = 0; r < 4; ++r) s[f][r] += lt[f];

    // online softmax update (row = g*4+r, reduce over 16 lanes of the group)
    float tmax[4];
#pragma unroll
    for (int r = 0; r < 4; ++r) {
      float v = fmaxf(fmaxf(s[0][r], s[1][r]), fmaxf(s[2][r], s[3][r]));
      v = fmaxf(v, __shfl_xor(v, 1));
      v = fmaxf(v, __shfl_xor(v, 2));
      v = fmaxf(v, __shfl_xor(v, 4));
      v = fmaxf(v, __shfl_xor(v, 8));
      tmax[r] = v;
    }
#pragma unroll
    for (int r = 0; r < 4; ++r) {
      float mn = fmaxf(mrow[r], tmax[r]);
      float sc = expf(mrow[r] - mn);
      mrow[r] = mn;
      lrow[r] *= sc;
#pragma unroll
      for (int n = 0; n < 4; ++n) acc[n][r] *= sc;
    }

    unsigned short* P = &sP[wid][0];
    float rs[4] = {0.f, 0.f, 0.f, 0.f};
#pragma unroll
    for (int f = 0; f < 4; ++f)
#pragma unroll
      for (int r = 0; r < 4; ++r) {
        float p = expf(s[f][r] - mrow[r]);
        rs[r] += p;
        P[(g * 4 + r) * 72 + f * 16 + rr] = f2bf(p);
      }
#pragma unroll
    for (int r = 0; r < 4; ++r) {
      float v = rs[r];
      v += __shfl_xor(v, 1); v += __shfl_xor(v, 2);
      v += __shfl_xor(v, 4); v += __shfl_xor(v, 8);
      lrow[r] += v;
    }

    // PV: acc[16q][64d] += P[16q][64k] * V[64k][64d]
#pragma unroll
    for (int kk = 0; kk < 2; ++kk) {
      bf16x8 pa = *(const bf16x8*)&P[rr * 72 + kk * 32 + g * 8];
#pragma unroll
      for (int n = 0; n < 4; ++n) {
        const int vrow = n * 16 + rr;
        const int cb = (kk * 64 + g * 16) ^ ((vrow & 7) << 4);
        bf16x8 bv = *(const bf16x8*)((const char*)&sV[cur][vrow * 64] + cb);
        acc[n] = __builtin_amdgcn_mfma_f32_16x16x32_bf16(pa, bv, acc[n], 0, 0, 0);
      }
    }
    cur ^= 1;
  }

  unsigned short* Ob = O + ((size_t)b * S + qt * 64 + wid * 16) * DM + h * DK;
#pragma unroll
  for (int n = 0; n < 4; ++n)
#pragma unroll
    for (int r = 0; r < 4; ++r) {
      const int q = g * 4 + r;
      const int d = n * 16 + rr;
      Ob[(size_t)q * DM + d] = f2bf(acc[n][r] / lrow[r]);
    }
}

// ---------------- launch ----------------
extern "C" void kernel_launch(void* const* d_in, const int* in_sizes, int n_in,
                              void* d_out, int out_size, void* d_ws, size_t ws_size,
                              hipStream_t stream) {
  const float* x      = (const float*)d_in[0];
  const float* coords = (const float*)d_in[1];
  const float* Wq = (const float*)d_in[2];
  const float* bq = (const float*)d_in[3];
  const float* Wk = (const float*)d_in[4];
  const float* bk = (const float*)d_in[5];
  const float* Wv = (const float*)d_in[6];
  const float* bv = (const float*)d_in[7];
  const float* Wo = (const float*)d_in[8];
  const float* bo = (const float*)d_in[9];

  const int S = in_sizes[1];                // 2048
  const int B = in_sizes[0] / (S * DM);     // 2
  const int M = B * S;                      // 4096

  char* w = (char*)d_ws;
  size_t off = 0;
  unsigned short* xb  = (unsigned short*)(w + off); off += (size_t)M * DM * 2;
  unsigned short* Wqb = (unsigned short*)(w + off); off += (size_t)DM * DM * 2;
  unsigned short* Wkb = (unsigned short*)(w + off); off += (size_t)DM * DM * 2;
  unsigned short* Wvb = (unsigned short*)(w + off); off += (size_t)DM * DM * 2;
  unsigned short* Wob = (unsigned short*)(w + off); off += (size_t)DM * DM * 2;
  unsigned short* Qb  = (unsigned short*)(w + off); off += (size_t)M * DM * 2;
  unsigned short* Kb  = (unsigned short*)(w + off); off += (size_t)M * DM * 2;
  unsigned short* Vb  = (unsigned short*)(w + off); off += (size_t)M * DM * 2;
  unsigned short* Vtb = (unsigned short*)(w + off); off += (size_t)M * DM * 2;
  unsigned short* Ob  = (unsigned short*)(w + off); off += (size_t)M * DM * 2;
  float* ltw = (float*)(w + off); off += (size_t)S * 4;
  float* bqs = (float*)(w + off); off += (size_t)DM * 4;
  (void)ws_size; (void)n_in; (void)out_size;

  // prep
  k_conv<<<(M * DM) / 1024, 256, 0, stream>>>(x, xb, M * DM, 1.0f);
  k_conv<<<(DM * DM) / 1024, 256, 0, stream>>>(Wq, Wqb, DM * DM, 0.125f);
  k_conv<<<(DM * DM) / 1024, 256, 0, stream>>>(Wk, Wkb, DM * DM, 1.0f);
  k_conv<<<(DM * DM) / 1024, 256, 0, stream>>>(Wv, Wvb, DM * DM, 1.0f);
  k_conv<<<(DM * DM) / 1024, 256, 0, stream>>>(Wo, Wob, DM * DM, 1.0f);
  k_scale_f32<<<(DM + 255) / 256, 256, 0, stream>>>(bq, bqs, DM, 0.125f);
  k_ltw<<<(S + 255) / 256, 256, 0, stream>>>(coords, ltw, S);

  // projections
  dim3 gg((M / BM) * (DM / BN));
  gemm_bt<0><<<gg, 256, 0, stream>>>(xb, Wqb, bqs, Qb, M, DM, DM);
  gemm_bt<0><<<gg, 256, 0, stream>>>(xb, Wkb, bk, Kb, M, DM, DM);
  gemm_bt<0><<<gg, 256, 0, stream>>>(xb, Wvb, bv, Vb, M, DM, DM);

  // V transpose + attention
  k_transpose<<<B * NHEAD * (S / 64), 256, 0, stream>>>(Vb, Vtb, S);
  k_attn<<<B * NHEAD * (S / 64), 256, 0, stream>>>(Qb, Kb, Vtb, ltw, Ob, S);

  // output projection (f32 out)
  gemm_bt<1><<<gg, 256, 0, stream>>>(Ob, Wob, bo, d_out, M, DM, DM);
}

// Round 2
// 190.320 us; speedup vs baseline: 1.4592x; 1.4592x over previous
//
#include <hip/hip_runtime.h>

#define DM 1024
#define NHEAD 16
#define DK 64
#define QLD 3072   // fused QKV row stride

typedef short bf16x8 __attribute__((ext_vector_type(8)));
typedef float f32x4 __attribute__((ext_vector_type(4)));

__device__ __forceinline__ unsigned short f2bf(float f) {
  union { float f; unsigned u; } v; v.f = f;
  return (unsigned short)((v.u + 0x7fffu + ((v.u >> 16) & 1u)) >> 16);
}
__device__ __forceinline__ float bf2f(unsigned short h) {
  union { unsigned u; float f; } v; v.u = ((unsigned)h) << 16; return v.f;
}

__device__ __forceinline__ void gld16(const void* g, void* l) {
  __builtin_amdgcn_global_load_lds((const __attribute__((address_space(1))) void*)g,
                                   (__attribute__((address_space(3))) void*)l, 16, 0, 0);
}

// ---------------- elementwise prep ----------------
__global__ void k_conv(const float* __restrict__ src, unsigned short* __restrict__ dst,
                       int n, float scale) {
  int i = (blockIdx.x * blockDim.x + threadIdx.x) * 4;
  if (i >= n) return;
  float4 v = *(const float4*)(src + i);
  ushort4 o;
  o.x = f2bf(v.x * scale); o.y = f2bf(v.y * scale);
  o.z = f2bf(v.z * scale); o.w = f2bf(v.w * scale);
  *(ushort4*)(dst + i) = o;
}

__global__ void k_bias(const float* __restrict__ bq, const float* __restrict__ bk,
                       const float* __restrict__ bv, float* __restrict__ bcat, float qs) {
  int i = blockIdx.x * blockDim.x + threadIdx.x;
  if (i >= 3 * DM) return;
  float v = (i < DM) ? bq[i] * qs : (i < 2 * DM ? bk[i - DM] : bv[i - 2 * DM]);
  bcat[i] = v;
}

// trapezoid weights: tw (natural order, f32) and twb (kappa-permuted, bf16)
__global__ void k_tw(const float* __restrict__ coords, float* __restrict__ tw,
                     unsigned short* __restrict__ twb, int S) {
  int s = blockIdx.x * blockDim.x + threadIdx.x;
  if (s >= S) return;
  auto twval = [&](int k) {
    float a = (k > 0)     ? fabsf(coords[k] - coords[k - 1]) : 0.f;
    float b = (k < S - 1) ? fabsf(coords[k + 1] - coords[k]) : 0.f;
    return 0.5f * (a + b);
  };
  tw[s] = twval(s);
  int pos = s & 63, kt = s >> 6;
  int key = (kt << 6) + ((pos & 3) << 4) + (pos >> 2);   // kappa
  twb[s] = f2bf(twval(key));
}

// ---------------- GEMM: C[M,N] = A[M,K] * B[N,K]^T + bias ----------------
#define BM 128
#define BN 128
#define BKK 64

template<int OUTF32>
__global__ __launch_bounds__(256)
void gemm_bt(const unsigned short* __restrict__ A, const unsigned short* __restrict__ B,
             const float* __restrict__ bias, void* __restrict__ C,
             int M, int N, int K, int ldc) {
  __shared__ __align__(16) unsigned short sA[2][BM * BKK];
  __shared__ __align__(16) unsigned short sB[2][BN * BKK];
  const int tid = threadIdx.x;
  const int lane = tid & 63;
  const int wid = tid >> 6;
  const int rr = lane & 15, g = lane >> 4;
  const int nbn = N / BN;
  const int bm = blockIdx.x / nbn, bn = blockIdx.x % nbn;
  const int wr = wid >> 1, wc = wid & 1;
  const int nkt = K / BKK;

  const unsigned short* Abase = A + (size_t)bm * BM * K;
  const unsigned short* Bbase = B + (size_t)bn * BN * K;

  auto stage = [&](int buf, int kt) {
#pragma unroll
    for (int j = 0; j < 4; ++j) {
      int o = j * 256 + tid;
      int row = o >> 3;
      int ce = (o & 7) * 8;
      gld16(Abase + (size_t)row * K + kt * BKK + ce, &sA[buf][o * 8]);
      gld16(Bbase + (size_t)row * K + kt * BKK + ce, &sB[buf][o * 8]);
    }
  };

  f32x4 acc[4][4] = {};
  stage(0, 0);
  int cur = 0;
  for (int kt = 0; kt < nkt; ++kt) {
    __syncthreads();
    if (kt + 1 < nkt) stage(cur ^ 1, kt + 1);
    const unsigned short* a0 = &sA[cur][(wr * 64) * BKK];
    const unsigned short* b0 = &sB[cur][(wc * 64) * BKK];
#pragma unroll
    for (int kk = 0; kk < 2; ++kk) {
      const int co = kk * 32 + g * 8;
      bf16x8 af[4], bfr[4];
#pragma unroll
      for (int m = 0; m < 4; ++m)
        af[m] = *(const bf16x8*)&a0[(m * 16 + rr) * BKK + co];
#pragma unroll
      for (int n = 0; n < 4; ++n)
        bfr[n] = *(const bf16x8*)&b0[(n * 16 + rr) * BKK + co];
#pragma unroll
      for (int m = 0; m < 4; ++m)
#pragma unroll
        for (int n = 0; n < 4; ++n)
          acc[m][n] = __builtin_amdgcn_mfma_f32_16x16x32_bf16(af[m], bfr[n], acc[m][n], 0, 0, 0);
    }
    cur ^= 1;
  }

  const int crow0 = bm * BM + wr * 64;
  const int ccol0 = bn * BN + wc * 64;
#pragma unroll
  for (int n = 0; n < 4; ++n) {
    const int col = ccol0 + n * 16 + rr;
    const float bn_ = bias ? bias[col] : 0.f;
#pragma unroll
    for (int m = 0; m < 4; ++m)
#pragma unroll
      for (int r = 0; r < 4; ++r) {
        const int row = crow0 + m * 16 + g * 4 + r;
        float v = acc[m][n][r] + bn_;
        if (OUTF32) ((float*)C)[(size_t)row * ldc + col] = v;
        else ((unsigned short*)C)[(size_t)row * ldc + col] = f2bf(v);
      }
  }
}

// ---------------- V transpose + tw prescale + kappa permute ----------------
// V region of QKV [B][S][QLD] -> Vt[B*H][DK][S], Vt[d][kt*64+pos] = V[kt*64+kappa(pos)][d]*tw
__global__ __launch_bounds__(256)
void k_transpose(const unsigned short* __restrict__ V, const float* __restrict__ tw,
                 unsigned short* __restrict__ Vt, int S, int ld) {
  __shared__ __align__(16) unsigned short t[64][72];
  __shared__ float tws[64];
  const int nst = S / 64;
  int st = blockIdx.x % nst;
  int bh = blockIdx.x / nst;
  int h = bh & (NHEAD - 1), b = bh / NHEAD;
  const unsigned short* src = V + ((size_t)b * S + st * 64) * ld + h * DK;
  unsigned short* dst = Vt + (size_t)bh * DK * S + st * 64;
  int tid = threadIdx.x;
  if (tid < 64) tws[tid] = tw[st * 64 + tid];
#pragma unroll
  for (int i = 0; i < 2; ++i) {
    int r = i * 32 + (tid >> 3);
    int c = (tid & 7) * 8;
    *(uint4*)&t[r][c] = *(const uint4*)&src[(size_t)r * ld + c];
  }
  __syncthreads();
#pragma unroll
  for (int i = 0; i < 2; ++i) {
    int d = i * 32 + (tid >> 3);
    int p0 = (tid & 7) * 8;
    unsigned short tmp[8];
#pragma unroll
    for (int j = 0; j < 8; ++j) {
      int p = p0 + j;
      int kl = ((p & 3) << 4) + (p >> 2);    // kappa within 64-tile
      tmp[j] = f2bf(bf2f(t[kl][d]) * tws[kl]);
    }
    *(uint4*)&dst[(size_t)d * S + p0] = *(const uint4*)&tmp[0];
  }
}

// ---------------- attention: p=exp2(s), denom via tw-MFMA ----------------
__global__ __launch_bounds__(256)
void k_attn(const unsigned short* __restrict__ QKV, const unsigned short* __restrict__ Vt,
            const unsigned short* __restrict__ twb, unsigned short* __restrict__ O, int S) {
  __shared__ __align__(16) unsigned short sK[2][64 * 64];
  __shared__ __align__(16) unsigned short sV[2][64 * 64];
  __shared__ __align__(16) unsigned short sP[4][16 * 72];
  const int tid = threadIdx.x, lane = tid & 63, wid = tid >> 6;
  const int rr = lane & 15, g = lane >> 4;
  const int nqt = S / 64;
  const int qt = blockIdx.x % nqt;
  const int bh = blockIdx.x / nqt;
  const int h = bh & (NHEAD - 1), b = bh / NHEAD;

  const unsigned short* Qbase = QKV + ((size_t)b * S + qt * 64 + wid * 16) * QLD + h * DK;
  const unsigned short* Kbase = QKV + (size_t)b * S * QLD + DM + h * DK;
  const unsigned short* Vbase = Vt + (size_t)bh * DK * S;

  bf16x8 aq0 = *(const bf16x8*)&Qbase[(size_t)rr * QLD + g * 8];
  bf16x8 aq1 = *(const bf16x8*)&Qbase[(size_t)rr * QLD + 32 + g * 8];

  f32x4 acc[5] = {};
  const f32x4 z0 = {};

  auto stage = [&](int buf, int kt) {
#pragma unroll
    for (int j = 0; j < 2; ++j) {
      int o = j * 256 + tid;
      int row = o >> 3;
      int cb = ((o & 7) * 16) ^ ((row & 7) << 4);
      gld16((const char*)(Kbase + (size_t)(kt * 64 + row) * QLD) + cb, &sK[buf][o * 8]);
      gld16((const char*)(Vbase + (size_t)row * S + kt * 64) + cb, &sV[buf][o * 8]);
    }
  };

  stage(0, 0);
  int cur = 0;
  const int nkt = S / 64;
  for (int kt = 0; kt < nkt; ++kt) {
    __syncthreads();
    if (kt + 1 < nkt) stage(cur ^ 1, kt + 1);

    // scores: 4 frags of 16x16, K=64 via 2 MFMAs each
    f32x4 s[4];
#pragma unroll
    for (int f = 0; f < 4; ++f) {
      const int row = f * 16 + rr;
      const int swz = (row & 7) << 4;
      bf16x8 k0 = *(const bf16x8*)((const char*)&sK[cur][row * 64] + ((g * 16) ^ swz));
      bf16x8 k1 = *(const bf16x8*)((const char*)&sK[cur][row * 64] + ((64 + g * 16) ^ swz));
      f32x4 z = __builtin_amdgcn_mfma_f32_16x16x32_bf16(aq0, k0, z0, 0, 0, 0);
      s[f] = __builtin_amdgcn_mfma_f32_16x16x32_bf16(aq1, k1, z, 0, 0, 0);
    }

    // p = exp2(s); pack 4 f-values (f-minor layout) into one b64 write per row
    unsigned short* P = &sP[wid][0];
#pragma unroll
    for (int r = 0; r < 4; ++r) {
      float p0 = exp2f(s[0][r]);
      float p1 = exp2f(s[1][r]);
      float p2 = exp2f(s[2][r]);
      float p3 = exp2f(s[3][r]);
      unsigned lo, hi;
      asm("v_cvt_pk_bf16_f32 %0, %1, %2" : "=v"(lo) : "v"(p0), "v"(p1));
      asm("v_cvt_pk_bf16_f32 %0, %1, %2" : "=v"(hi) : "v"(p2), "v"(p3));
      uint2 w2; w2.x = lo; w2.y = hi;
      *(uint2*)((char*)P + (g * 4 + r) * 144 + rr * 8) = w2;
    }

    // tw fragments for denominator (kappa-ordered, matches P/V slot order)
    bf16x8 tw0 = *(const bf16x8*)&twb[kt * 64 + g * 8];
    bf16x8 tw1 = *(const bf16x8*)&twb[kt * 64 + 32 + g * 8];

    // PV + denominator
#pragma unroll
    for (int kk = 0; kk < 2; ++kk) {
      bf16x8 pa = *(const bf16x8*)&P[rr * 72 + kk * 32 + g * 8];
#pragma unroll
      for (int n = 0; n < 4; ++n) {
        const int vrow = n * 16 + rr;
        const int cb = (kk * 64 + g * 16) ^ ((vrow & 7) << 4);
        bf16x8 bv = *(const bf16x8*)((const char*)&sV[cur][vrow * 64] + cb);
        acc[n] = __builtin_amdgcn_mfma_f32_16x16x32_bf16(pa, bv, acc[n], 0, 0, 0);
      }
      acc[4] = __builtin_amdgcn_mfma_f32_16x16x32_bf16(pa, kk ? tw1 : tw0, acc[4], 0, 0, 0);
    }
    cur ^= 1;
  }

  unsigned short* Ob = O + ((size_t)b * S + qt * 64 + wid * 16) * DM + h * DK;
#pragma unroll
  for (int n = 0; n < 4; ++n)
#pragma unroll
    for (int r = 0; r < 4; ++r) {
      const int q = g * 4 + r;
      const int d = n * 16 + rr;
      Ob[(size_t)q * DM + d] = f2bf(acc[n][r] / acc[4][r]);
    }
}

// ---------------- launch ----------------
extern "C" void kernel_launch(void* const* d_in, const int* in_sizes, int n_in,
                              void* d_out, int out_size, void* d_ws, size_t ws_size,
                              hipStream_t stream) {
  const float* x      = (const float*)d_in[0];
  const float* coords = (const float*)d_in[1];
  const float* Wq = (const float*)d_in[2];
  const float* bq = (const float*)d_in[3];
  const float* Wk = (const float*)d_in[4];
  const float* bk = (const float*)d_in[5];
  const float* Wv = (const float*)d_in[6];
  const float* bv = (const float*)d_in[7];
  const float* Wo = (const float*)d_in[8];
  const float* bo = (const float*)d_in[9];

  const int S = in_sizes[1];
  const int B = in_sizes[0] / (S * DM);
  const int M = B * S;
  const float QS = 0.18033688011112042f;   // log2(e)/8

  char* w = (char*)d_ws;
  size_t off = 0;
  unsigned short* xb   = (unsigned short*)(w + off); off += (size_t)M * DM * 2;   // aliased: Ob after QKV gemm
  unsigned short* Wcat = (unsigned short*)(w + off); off += (size_t)3 * DM * DM * 2;
  unsigned short* Wob  = (unsigned short*)(w + off); off += (size_t)DM * DM * 2;
  unsigned short* QKVb = (unsigned short*)(w + off); off += (size_t)M * QLD * 2;
  unsigned short* Vtb  = (unsigned short*)(w + off); off += (size_t)M * DM * 2;
  float* tw  = (float*)(w + off); off += (size_t)S * 4;
  unsigned short* twb = (unsigned short*)(w + off); off += (size_t)S * 2;
  float* bcat = (float*)(w + off); off += (size_t)3 * DM * 4;
  unsigned short* Ob = xb;   // alias: xb dead after QKV gemm
  (void)ws_size; (void)n_in; (void)out_size;

  // prep
  k_conv<<<(M * DM) / 1024, 256, 0, stream>>>(x, xb, M * DM, 1.0f);
  k_conv<<<(DM * DM) / 1024, 256, 0, stream>>>(Wq, Wcat, DM * DM, QS);
  k_conv<<<(DM * DM) / 1024, 256, 0, stream>>>(Wk, Wcat + DM * DM, DM * DM, 1.0f);
  k_conv<<<(DM * DM) / 1024, 256, 0, stream>>>(Wv, Wcat + 2 * DM * DM, DM * DM, 1.0f);
  k_conv<<<(DM * DM) / 1024, 256, 0, stream>>>(Wo, Wob, DM * DM, 1.0f);
  k_bias<<<(3 * DM + 255) / 256, 256, 0, stream>>>(bq, bk, bv, bcat, QS);
  k_tw<<<(S + 255) / 256, 256, 0, stream>>>(coords, tw, twb, S);

  // fused QKV projection: [M,1024] x [3072,1024]^T -> [M,3072]
  gemm_bt<0><<<(M / BM) * (3 * DM / BN), 256, 0, stream>>>(xb, Wcat, bcat, QKVb, M, 3 * DM, DM, QLD);

  // V transpose (+ tw prescale, kappa permute) + attention
  k_transpose<<<B * NHEAD * (S / 64), 256, 0, stream>>>(QKVb + 2 * DM, tw, Vtb, S, QLD);
  k_attn<<<B * NHEAD * (S / 64), 256, 0, stream>>>(QKVb, Vtb, twb, Ob, S);

  // output projection (f32 out)
  gemm_bt<1><<<(M / BM) * (DM / BN), 256, 0, stream>>>(Ob, Wob, bo, d_out, M, DM, DM, DM);
}

// Round 3
// 166.502 us; speedup vs baseline: 1.6679x; 1.1431x over previous
//
#include <hip/hip_runtime.h>

#define DM 1024
#define NHEAD 16
#define DK 64
#define QLD 3072   // fused QKV row stride

typedef short bf16x8 __attribute__((ext_vector_type(8)));
typedef float f32x4 __attribute__((ext_vector_type(4)));

__device__ __forceinline__ unsigned short f2bf(float f) {
  union { float f; unsigned u; } v; v.f = f;
  return (unsigned short)((v.u + 0x7fffu + ((v.u >> 16) & 1u)) >> 16);
}
__device__ __forceinline__ float bf2f(unsigned short h) {
  union { unsigned u; float f; } v; v.u = ((unsigned)h) << 16; return v.f;
}

__device__ __forceinline__ void gld16(const void* g, void* l) {
  __builtin_amdgcn_global_load_lds((const __attribute__((address_space(1))) void*)g,
                                   (__attribute__((address_space(3))) void*)l, 16, 0, 0);
}

// ---------------- elementwise prep ----------------
__global__ void k_conv(const float* __restrict__ src, unsigned short* __restrict__ dst,
                       int n, float scale) {
  int i = (blockIdx.x * blockDim.x + threadIdx.x) * 4;
  if (i >= n) return;
  float4 v = *(const float4*)(src + i);
  ushort4 o;
  o.x = f2bf(v.x * scale); o.y = f2bf(v.y * scale);
  o.z = f2bf(v.z * scale); o.w = f2bf(v.w * scale);
  *(ushort4*)(dst + i) = o;
}

__global__ void k_bias(const float* __restrict__ bq, const float* __restrict__ bk,
                       const float* __restrict__ bv, float* __restrict__ bcat, float qs) {
  int i = blockIdx.x * blockDim.x + threadIdx.x;
  if (i >= 3 * DM) return;
  float v = (i < DM) ? bq[i] * qs : (i < 2 * DM ? bk[i - DM] : bv[i - 2 * DM]);
  bcat[i] = v;
}

// trapezoid weights: tw (natural order, f32) and twb (kappa-permuted, bf16)
__global__ void k_tw(const float* __restrict__ coords, float* __restrict__ tw,
                     unsigned short* __restrict__ twb, int S) {
  int s = blockIdx.x * blockDim.x + threadIdx.x;
  if (s >= S) return;
  auto twval = [&](int k) {
    float a = (k > 0)     ? fabsf(coords[k] - coords[k - 1]) : 0.f;
    float b = (k < S - 1) ? fabsf(coords[k + 1] - coords[k]) : 0.f;
    return 0.5f * (a + b);
  };
  tw[s] = twval(s);
  int pos = s & 63, kt = s >> 6;
  int key = (kt << 6) + ((pos & 3) << 4) + (pos >> 2);   // kappa
  twb[s] = f2bf(twval(key));
}

// ---------------- GEMM: C[M,N] = A[M,K] * B[N,K]^T + bias ----------------
#define BM 128
#define BN 128
#define BKK 64

template<int OUTF32>
__global__ __launch_bounds__(256)
void gemm_bt(const unsigned short* __restrict__ A, const unsigned short* __restrict__ B,
             const float* __restrict__ bias, void* __restrict__ C,
             int M, int N, int K, int ldc) {
  __shared__ __align__(16) unsigned short sA[2][BM * BKK];
  __shared__ __align__(16) unsigned short sB[2][BN * BKK];
  const int tid = threadIdx.x;
  const int lane = tid & 63;
  const int wid = tid >> 6;
  const int rr = lane & 15, g = lane >> 4;
  const int nbn = N / BN;
  const int bm = blockIdx.x / nbn, bn = blockIdx.x % nbn;
  const int wr = wid >> 1, wc = wid & 1;
  const int nkt = K / BKK;

  const unsigned short* Abase = A + (size_t)bm * BM * K;
  const unsigned short* Bbase = B + (size_t)bn * BN * K;

  auto stage = [&](int buf, int kt) {
#pragma unroll
    for (int j = 0; j < 4; ++j) {
      int o = j * 256 + tid;
      int row = o >> 3;
      int ce = (o & 7) * 8;
      gld16(Abase + (size_t)row * K + kt * BKK + ce, &sA[buf][o * 8]);
      gld16(Bbase + (size_t)row * K + kt * BKK + ce, &sB[buf][o * 8]);
    }
  };

  f32x4 acc[4][4] = {};
  stage(0, 0);
  int cur = 0;
  for (int kt = 0; kt < nkt; ++kt) {
    __syncthreads();
    if (kt + 1 < nkt) stage(cur ^ 1, kt + 1);
    const unsigned short* a0 = &sA[cur][(wr * 64) * BKK];
    const unsigned short* b0 = &sB[cur][(wc * 64) * BKK];
#pragma unroll
    for (int kk = 0; kk < 2; ++kk) {
      const int co = kk * 32 + g * 8;
      bf16x8 af[4], bfr[4];
#pragma unroll
      for (int m = 0; m < 4; ++m)
        af[m] = *(const bf16x8*)&a0[(m * 16 + rr) * BKK + co];
#pragma unroll
      for (int n = 0; n < 4; ++n)
        bfr[n] = *(const bf16x8*)&b0[(n * 16 + rr) * BKK + co];
#pragma unroll
      for (int m = 0; m < 4; ++m)
#pragma unroll
        for (int n = 0; n < 4; ++n)
          acc[m][n] = __builtin_amdgcn_mfma_f32_16x16x32_bf16(af[m], bfr[n], acc[m][n], 0, 0, 0);
    }
    cur ^= 1;
  }

  const int crow0 = bm * BM + wr * 64;
  const int ccol0 = bn * BN + wc * 64;
#pragma unroll
  for (int n = 0; n < 4; ++n) {
    const int col = ccol0 + n * 16 + rr;
    const float bn_ = bias ? bias[col] : 0.f;
#pragma unroll
    for (int m = 0; m < 4; ++m)
#pragma unroll
      for (int r = 0; r < 4; ++r) {
        const int row = crow0 + m * 16 + g * 4 + r;
        float v = acc[m][n][r] + bn_;
        if (OUTF32) ((float*)C)[(size_t)row * ldc + col] = v;
        else ((unsigned short*)C)[(size_t)row * ldc + col] = f2bf(v);
      }
  }
}

// ---------------- V transpose + tw prescale + kappa permute ----------------
__global__ __launch_bounds__(256)
void k_transpose(const unsigned short* __restrict__ V, const float* __restrict__ tw,
                 unsigned short* __restrict__ Vt, int S, int ld) {
  __shared__ __align__(16) unsigned short t[64][72];
  __shared__ float tws[64];
  const int nst = S / 64;
  int st = blockIdx.x % nst;
  int bh = blockIdx.x / nst;
  int h = bh & (NHEAD - 1), b = bh / NHEAD;
  const unsigned short* src = V + ((size_t)b * S + st * 64) * ld + h * DK;
  unsigned short* dst = Vt + (size_t)bh * DK * S + st * 64;
  int tid = threadIdx.x;
  if (tid < 64) tws[tid] = tw[st * 64 + tid];
#pragma unroll
  for (int i = 0; i < 2; ++i) {
    int r = i * 32 + (tid >> 3);
    int c = (tid & 7) * 8;
    *(uint4*)&t[r][c] = *(const uint4*)&src[(size_t)r * ld + c];
  }
  __syncthreads();
#pragma unroll
  for (int i = 0; i < 2; ++i) {
    int d = i * 32 + (tid >> 3);
    int p0 = (tid & 7) * 8;
    unsigned short tmp[8];
#pragma unroll
    for (int j = 0; j < 8; ++j) {
      int p = p0 + j;
      int kl = ((p & 3) << 4) + (p >> 2);    // kappa within 64-tile
      tmp[j] = f2bf(bf2f(t[kl][d]) * tws[kl]);
    }
    *(uint4*)&dst[(size_t)d * S + p0] = *(const uint4*)&tmp[0];
  }
}

// ---------------- attention: p=exp2(s), denom via tw-MFMA ----------------
// 4 waves x 32 q-rows = 128 q-rows per block; KVBLK=64.
__global__ __launch_bounds__(256)
void k_attn(const unsigned short* __restrict__ QKV, const unsigned short* __restrict__ Vt,
            const unsigned short* __restrict__ twb, unsigned short* __restrict__ O, int S) {
  __shared__ __align__(16) unsigned short sK[2][64 * 64];
  __shared__ __align__(16) unsigned short sV[2][64 * 64];
  __shared__ __align__(16) unsigned short sP[4][32 * 72];
  const int tid = threadIdx.x, lane = tid & 63, wid = tid >> 6;
  const int rr = lane & 15, g = lane >> 4;
  const int nqt = S / 128;
  // bijective XCD swizzle: cluster the blocks sharing one (b,h)'s K/V on one XCD
  const int cpx = gridDim.x >> 3;
  const int swz = (blockIdx.x & 7) * cpx + (blockIdx.x >> 3);
  const int qt = swz % nqt;
  const int bh = swz / nqt;
  const int h = bh & (NHEAD - 1), b = bh / NHEAD;

  const unsigned short* Qbase = QKV + ((size_t)b * S + qt * 128 + wid * 32) * QLD + h * DK;
  const unsigned short* Kbase = QKV + (size_t)b * S * QLD + DM + h * DK;
  const unsigned short* Vbase = Vt + (size_t)bh * DK * S;

  bf16x8 aq[2][2];
#pragma unroll
  for (int qm = 0; qm < 2; ++qm) {
    aq[qm][0] = *(const bf16x8*)&Qbase[(size_t)(qm * 16 + rr) * QLD + g * 8];
    aq[qm][1] = *(const bf16x8*)&Qbase[(size_t)(qm * 16 + rr) * QLD + 32 + g * 8];
  }

  f32x4 acc[2][5] = {};
  const f32x4 z0 = {};

  auto stage = [&](int buf, int kt) {
#pragma unroll
    for (int j = 0; j < 2; ++j) {
      int o = j * 256 + tid;
      int row = o >> 3;
      int cb = ((o & 7) * 16) ^ ((row & 7) << 4);
      gld16((const char*)(Kbase + (size_t)(kt * 64 + row) * QLD) + cb, &sK[buf][o * 8]);
      gld16((const char*)(Vbase + (size_t)row * S + kt * 64) + cb, &sV[buf][o * 8]);
    }
  };

  stage(0, 0);
  int cur = 0;
  const int nkt = S / 64;
  for (int kt = 0; kt < nkt; ++kt) {
    __syncthreads();
    if (kt + 1 < nkt) stage(cur ^ 1, kt + 1);

    // scores: S[32q][64k]; per f-frag read K once, reuse for both q-subtiles
    f32x4 s[2][4];
#pragma unroll
    for (int f = 0; f < 4; ++f) {
      const int row = f * 16 + rr;
      const int swzb = (row & 7) << 4;
      bf16x8 k0 = *(const bf16x8*)((const char*)&sK[cur][row * 64] + ((g * 16) ^ swzb));
      bf16x8 k1 = *(const bf16x8*)((const char*)&sK[cur][row * 64] + ((64 + g * 16) ^ swzb));
#pragma unroll
      for (int qm = 0; qm < 2; ++qm) {
        f32x4 z = __builtin_amdgcn_mfma_f32_16x16x32_bf16(aq[qm][0], k0, z0, 0, 0, 0);
        s[qm][f] = __builtin_amdgcn_mfma_f32_16x16x32_bf16(aq[qm][1], k1, z, 0, 0, 0);
      }
    }

    // p = exp2(s); pack 4 f-values (f-minor kappa layout) into one b64 write per row
    unsigned short* P = &sP[wid][0];
#pragma unroll
    for (int qm = 0; qm < 2; ++qm)
#pragma unroll
      for (int r = 0; r < 4; ++r) {
        float p0 = exp2f(s[qm][0][r]);
        float p1 = exp2f(s[qm][1][r]);
        float p2 = exp2f(s[qm][2][r]);
        float p3 = exp2f(s[qm][3][r]);
        unsigned lo, hi;
        asm("v_cvt_pk_bf16_f32 %0, %1, %2" : "=v"(lo) : "v"(p0), "v"(p1));
        asm("v_cvt_pk_bf16_f32 %0, %1, %2" : "=v"(hi) : "v"(p2), "v"(p3));
        uint2 w2; w2.x = lo; w2.y = hi;
        *(uint2*)((char*)P + (qm * 16 + g * 4 + r) * 144 + rr * 8) = w2;
      }

    // tw fragments for denominator (kappa-ordered, matches P/V slot order)
    bf16x8 tw0 = *(const bf16x8*)&twb[kt * 64 + g * 8];
    bf16x8 tw1 = *(const bf16x8*)&twb[kt * 64 + 32 + g * 8];

    // PV + denominator: V frags reused across both q-subtiles
#pragma unroll
    for (int kk = 0; kk < 2; ++kk) {
      bf16x8 pa[2];
#pragma unroll
      for (int qm = 0; qm < 2; ++qm)
        pa[qm] = *(const bf16x8*)&P[(qm * 16 + rr) * 72 + kk * 32 + g * 8];
#pragma unroll
      for (int n = 0; n < 4; ++n) {
        const int vrow = n * 16 + rr;
        const int cb = (kk * 64 + g * 16) ^ ((vrow & 7) << 4);
        bf16x8 bv = *(const bf16x8*)((const char*)&sV[cur][vrow * 64] + cb);
#pragma unroll
        for (int qm = 0; qm < 2; ++qm)
          acc[qm][n] = __builtin_amdgcn_mfma_f32_16x16x32_bf16(pa[qm], bv, acc[qm][n], 0, 0, 0);
      }
#pragma unroll
      for (int qm = 0; qm < 2; ++qm)
        acc[qm][4] = __builtin_amdgcn_mfma_f32_16x16x32_bf16(pa[qm], kk ? tw1 : tw0, acc[qm][4], 0, 0, 0);
    }
    cur ^= 1;
  }

  unsigned short* Ob = O + ((size_t)b * S + qt * 128 + wid * 32) * DM + h * DK;
#pragma unroll
  for (int qm = 0; qm < 2; ++qm)
#pragma unroll
    for (int n = 0; n < 4; ++n)
#pragma unroll
      for (int r = 0; r < 4; ++r) {
        const int q = qm * 16 + g * 4 + r;
        const int d = n * 16 + rr;
        Ob[(size_t)q * DM + d] = f2bf(acc[qm][n][r] / acc[qm][4][r]);
      }
}

// ---------------- launch ----------------
extern "C" void kernel_launch(void* const* d_in, const int* in_sizes, int n_in,
                              void* d_out, int out_size, void* d_ws, size_t ws_size,
                              hipStream_t stream) {
  const float* x      = (const float*)d_in[0];
  const float* coords = (const float*)d_in[1];
  const float* Wq = (const float*)d_in[2];
  const float* bq = (const float*)d_in[3];
  const float* Wk = (const float*)d_in[4];
  const float* bk = (const float*)d_in[5];
  const float* Wv = (const float*)d_in[6];
  const float* bv = (const float*)d_in[7];
  const float* Wo = (const float*)d_in[8];
  const float* bo = (const float*)d_in[9];

  const int S = in_sizes[1];
  const int B = in_sizes[0] / (S * DM);
  const int M = B * S;
  const float QS = 0.18033688011112042f;   // log2(e)/8

  char* w = (char*)d_ws;
  size_t off = 0;
  unsigned short* xb   = (unsigned short*)(w + off); off += (size_t)M * DM * 2;
  unsigned short* Wcat = (unsigned short*)(w + off); off += (size_t)3 * DM * DM * 2;
  unsigned short* Wob  = (unsigned short*)(w + off); off += (size_t)DM * DM * 2;
  unsigned short* QKVb = (unsigned short*)(w + off); off += (size_t)M * QLD * 2;
  unsigned short* Vtb  = (unsigned short*)(w + off); off += (size_t)M * DM * 2;
  float* tw  = (float*)(w + off); off += (size_t)S * 4;
  unsigned short* twb = (unsigned short*)(w + off); off += (size_t)S * 2;
  float* bcat = (float*)(w + off); off += (size_t)3 * DM * 4;
  unsigned short* Ob = xb;   // alias: xb dead after QKV gemm
  (void)ws_size; (void)n_in; (void)out_size;

  // prep
  k_conv<<<(M * DM) / 1024, 256, 0, stream>>>(x, xb, M * DM, 1.0f);
  k_conv<<<(DM * DM) / 1024, 256, 0, stream>>>(Wq, Wcat, DM * DM, QS);
  k_conv<<<(DM * DM) / 1024, 256, 0, stream>>>(Wk, Wcat + DM * DM, DM * DM, 1.0f);
  k_conv<<<(DM * DM) / 1024, 256, 0, stream>>>(Wv, Wcat + 2 * DM * DM, DM * DM, 1.0f);
  k_conv<<<(DM * DM) / 1024, 256, 0, stream>>>(Wo, Wob, DM * DM, 1.0f);
  k_bias<<<(3 * DM + 255) / 256, 256, 0, stream>>>(bq, bk, bv, bcat, QS);
  k_tw<<<(S + 255) / 256, 256, 0, stream>>>(coords, tw, twb, S);

  // fused QKV projection: [M,1024] x [3072,1024]^T -> [M,3072]
  gemm_bt<0><<<(M / BM) * (3 * DM / BN), 256, 0, stream>>>(xb, Wcat, bcat, QKVb, M, 3 * DM, DM, QLD);

  // V transpose (+ tw prescale, kappa permute) + attention
  k_transpose<<<B * NHEAD * (S / 64), 256, 0, stream>>>(QKVb + 2 * DM, tw, Vtb, S, QLD);
  k_attn<<<B * NHEAD * (S / 128), 256, 0, stream>>>(QKVb, Vtb, twb, Ob, S);

  // output projection (f32 out)
  gemm_bt<1><<<(M / BM) * (DM / BN), 256, 0, stream>>>(Ob, Wob, bo, d_out, M, DM, DM, DM);
}

// Round 4
// 139.197 us; speedup vs baseline: 1.9951x; 1.1962x over previous
//
#include <hip/hip_runtime.h>

#define DM 1024
#define NHEAD 16
#define DK 64
#define QLD 3072   // fused QKV row stride

typedef short bf16x8 __attribute__((ext_vector_type(8)));
typedef float f32x4 __attribute__((ext_vector_type(4)));

__device__ __forceinline__ unsigned short f2bf(float f) {
  union { float f; unsigned u; } v; v.f = f;
  return (unsigned short)((v.u + 0x7fffu + ((v.u >> 16) & 1u)) >> 16);
}
__device__ __forceinline__ float bf2f(unsigned short h) {
  union { unsigned u; float f; } v; v.u = ((unsigned)h) << 16; return v.f;
}
__device__ __forceinline__ float fexp2(float x) {   // bare v_exp_f32: args bounded, no fixup needed
  float r; asm("v_exp_f32 %0, %1" : "=v"(r) : "v"(x)); return r;
}

__device__ __forceinline__ void gld16(const void* g, void* l) {
  __builtin_amdgcn_global_load_lds((const __attribute__((address_space(1))) void*)g,
                                   (__attribute__((address_space(3))) void*)l, 16, 0, 0);
}

// ---------------- fused prep: x conv + 4 weight convs + bias cat + tw ----------------
__global__ void k_prep(const float* __restrict__ x, const float* __restrict__ Wq,
                       const float* __restrict__ Wk, const float* __restrict__ Wv,
                       const float* __restrict__ Wo, const float* __restrict__ bq,
                       const float* __restrict__ bk, const float* __restrict__ bv,
                       const float* __restrict__ coords,
                       unsigned short* __restrict__ xb, unsigned short* __restrict__ Wcat,
                       unsigned short* __restrict__ Wob, float* __restrict__ bcat,
                       float* __restrict__ tw, unsigned short* __restrict__ twb,
                       int M, int S, float QS) {
  const int nx = M * DM / 4;       // x float4 count
  const int nw = DM * DM / 4;      // per-weight float4 count
  const int total = nx + 4 * nw;
  int gid = blockIdx.x * 256 + threadIdx.x;

  auto conv4 = [&](const float* src, unsigned short* dst, int idx, float sc) {
    float4 v = *(const float4*)(src + idx * 4);
    ushort4 o;
    o.x = f2bf(v.x * sc); o.y = f2bf(v.y * sc);
    o.z = f2bf(v.z * sc); o.w = f2bf(v.w * sc);
    *(ushort4*)(dst + idx * 4) = o;
  };

  if (gid < nx) { conv4(x, xb, gid, 1.0f); return; }
  if (gid < nx + nw) { conv4(Wq, Wcat, gid - nx, QS); return; }
  if (gid < nx + 2 * nw) { conv4(Wk, Wcat + DM * DM, gid - nx - nw, 1.0f); return; }
  if (gid < nx + 3 * nw) { conv4(Wv, Wcat + 2 * DM * DM, gid - nx - 2 * nw, 1.0f); return; }
  if (gid < total) { conv4(Wo, Wob, gid - nx - 3 * nw, 1.0f); return; }

  int r = gid - total;
  if (r < 3 * DM) {
    float v = (r < DM) ? bq[r] * QS : (r < 2 * DM ? bk[r - DM] : bv[r - 2 * DM]);
    bcat[r] = v;
    return;
  }
  r -= 3 * DM;
  if (r < S) {
    auto twval = [&](int k) {
      float a = (k > 0)     ? fabsf(coords[k] - coords[k - 1]) : 0.f;
      float b = (k < S - 1) ? fabsf(coords[k + 1] - coords[k]) : 0.f;
      return 0.5f * (a + b);
    };
    tw[r] = twval(r);
    int pos = r & 63, kt = r >> 6;
    int key = (kt << 6) + ((pos & 3) << 4) + (pos >> 2);   // kappa
    twb[r] = f2bf(twval(key));
  }
}

// ---------------- GEMM: C[M,N] = A[M,K] * B[N,K]^T + bias ----------------
#define BM 128
#define BN 128
#define BKK 64

template<int OUTF32>
__global__ __launch_bounds__(256)
void gemm_bt(const unsigned short* __restrict__ A, const unsigned short* __restrict__ B,
             const float* __restrict__ bias, void* __restrict__ C,
             int M, int N, int K, int ldc) {
  __shared__ __align__(16) unsigned short sA[2][BM * BKK];
  __shared__ __align__(16) unsigned short sB[2][BN * BKK];
  const int tid = threadIdx.x;
  const int lane = tid & 63;
  const int wid = tid >> 6;
  const int rr = lane & 15, g = lane >> 4;
  const int nbn = N / BN;
  // bijective XCD swizzle (grid % 8 == 0 for all our shapes)
  const int cpx = gridDim.x >> 3;
  const int bid = ((gridDim.x & 7) == 0) ? (blockIdx.x & 7) * cpx + (blockIdx.x >> 3)
                                         : blockIdx.x;
  const int bm = bid / nbn, bn = bid % nbn;
  const int wr = wid >> 1, wc = wid & 1;
  const int nkt = K / BKK;

  const unsigned short* Abase = A + (size_t)bm * BM * K;
  const unsigned short* Bbase = B + (size_t)bn * BN * K;

  auto stage = [&](int buf, int kt) {
#pragma unroll
    for (int j = 0; j < 4; ++j) {
      int o = j * 256 + tid;
      int row = o >> 3;
      int ce = (o & 7) * 8;
      gld16(Abase + (size_t)row * K + kt * BKK + ce, &sA[buf][o * 8]);
      gld16(Bbase + (size_t)row * K + kt * BKK + ce, &sB[buf][o * 8]);
    }
  };

  f32x4 acc[4][4] = {};
  stage(0, 0);
  int cur = 0;
  for (int kt = 0; kt < nkt; ++kt) {
    __syncthreads();
    if (kt + 1 < nkt) stage(cur ^ 1, kt + 1);
    const unsigned short* a0 = &sA[cur][(wr * 64) * BKK];
    const unsigned short* b0 = &sB[cur][(wc * 64) * BKK];
#pragma unroll
    for (int kk = 0; kk < 2; ++kk) {
      const int co = kk * 32 + g * 8;
      bf16x8 af[4], bfr[4];
#pragma unroll
      for (int m = 0; m < 4; ++m)
        af[m] = *(const bf16x8*)&a0[(m * 16 + rr) * BKK + co];
#pragma unroll
      for (int n = 0; n < 4; ++n)
        bfr[n] = *(const bf16x8*)&b0[(n * 16 + rr) * BKK + co];
      __builtin_amdgcn_s_setprio(1);
#pragma unroll
      for (int m = 0; m < 4; ++m)
#pragma unroll
        for (int n = 0; n < 4; ++n)
          acc[m][n] = __builtin_amdgcn_mfma_f32_16x16x32_bf16(af[m], bfr[n], acc[m][n], 0, 0, 0);
      __builtin_amdgcn_s_setprio(0);
    }
    cur ^= 1;
  }

  const int crow0 = bm * BM + wr * 64;
  const int ccol0 = bn * BN + wc * 64;
#pragma unroll
  for (int n = 0; n < 4; ++n) {
    const int col = ccol0 + n * 16 + rr;
    const float bn_ = bias ? bias[col] : 0.f;
#pragma unroll
    for (int m = 0; m < 4; ++m)
#pragma unroll
      for (int r = 0; r < 4; ++r) {
        const int row = crow0 + m * 16 + g * 4 + r;
        float v = acc[m][n][r] + bn_;
        if (OUTF32) ((float*)C)[(size_t)row * ldc + col] = v;
        else ((unsigned short*)C)[(size_t)row * ldc + col] = f2bf(v);
      }
  }
}

// ---------------- V transpose + tw prescale + kappa permute ----------------
__global__ __launch_bounds__(256)
void k_transpose(const unsigned short* __restrict__ V, const float* __restrict__ tw,
                 unsigned short* __restrict__ Vt, int S, int ld) {
  __shared__ __align__(16) unsigned short t[64][72];
  __shared__ float tws[64];
  const int nst = S / 64;
  int st = blockIdx.x % nst;
  int bh = blockIdx.x / nst;
  int h = bh & (NHEAD - 1), b = bh / NHEAD;
  const unsigned short* src = V + ((size_t)b * S + st * 64) * ld + h * DK;
  unsigned short* dst = Vt + (size_t)bh * DK * S + st * 64;
  int tid = threadIdx.x;
  if (tid < 64) tws[tid] = tw[st * 64 + tid];
#pragma unroll
  for (int i = 0; i < 2; ++i) {
    int r = i * 32 + (tid >> 3);
    int c = (tid & 7) * 8;
    *(uint4*)&t[r][c] = *(const uint4*)&src[(size_t)r * ld + c];
  }
  __syncthreads();
#pragma unroll
  for (int i = 0; i < 2; ++i) {
    int d = i * 32 + (tid >> 3);
    int p0 = (tid & 7) * 8;
    unsigned short tmp[8];
#pragma unroll
    for (int j = 0; j < 8; ++j) {
      int p = p0 + j;
      int kl = ((p & 3) << 4) + (p >> 2);    // kappa within 64-tile
      tmp[j] = f2bf(bf2f(t[kl][d]) * tws[kl]);
    }
    *(uint4*)&dst[(size_t)d * S + p0] = *(const uint4*)&tmp[0];
  }
}

// ---------------- attention: p=exp2(s), denom via tw-MFMA ----------------
// 4 waves x 32 q-rows = 128 q-rows per block; KVBLK=64.
__global__ __launch_bounds__(256)
void k_attn(const unsigned short* __restrict__ QKV, const unsigned short* __restrict__ Vt,
            const unsigned short* __restrict__ twb, unsigned short* __restrict__ O, int S) {
  __shared__ __align__(16) unsigned short sK[2][64 * 64];
  __shared__ __align__(16) unsigned short sV[2][64 * 64];
  __shared__ __align__(16) unsigned short sP[4][32 * 72];
  const int tid = threadIdx.x, lane = tid & 63, wid = tid >> 6;
  const int rr = lane & 15, g = lane >> 4;
  const int nqt = S / 128;
  // bijective XCD swizzle: cluster the blocks sharing one (b,h)'s K/V on one XCD
  const int cpx = gridDim.x >> 3;
  const int swz = (blockIdx.x & 7) * cpx + (blockIdx.x >> 3);
  const int qt = swz % nqt;
  const int bh = swz / nqt;
  const int h = bh & (NHEAD - 1), b = bh / NHEAD;

  const unsigned short* Qbase = QKV + ((size_t)b * S + qt * 128 + wid * 32) * QLD + h * DK;
  const unsigned short* Kbase = QKV + (size_t)b * S * QLD + DM + h * DK;
  const unsigned short* Vbase = Vt + (size_t)bh * DK * S;

  bf16x8 aq[2][2];
#pragma unroll
  for (int qm = 0; qm < 2; ++qm) {
    aq[qm][0] = *(const bf16x8*)&Qbase[(size_t)(qm * 16 + rr) * QLD + g * 8];
    aq[qm][1] = *(const bf16x8*)&Qbase[(size_t)(qm * 16 + rr) * QLD + 32 + g * 8];
  }

  f32x4 acc[2][5] = {};
  const f32x4 z0 = {};

  auto stage = [&](int buf, int kt) {
#pragma unroll
    for (int j = 0; j < 2; ++j) {
      int o = j * 256 + tid;
      int row = o >> 3;
      int cb = ((o & 7) * 16) ^ ((row & 7) << 4);
      gld16((const char*)(Kbase + (size_t)(kt * 64 + row) * QLD) + cb, &sK[buf][o * 8]);
      gld16((const char*)(Vbase + (size_t)row * S + kt * 64) + cb, &sV[buf][o * 8]);
    }
  };

  stage(0, 0);
  int cur = 0;
  const int nkt = S / 64;
  for (int kt = 0; kt < nkt; ++kt) {
    __syncthreads();
    if (kt + 1 < nkt) stage(cur ^ 1, kt + 1);

    // scores: S[32q][64k]; per f-frag read K once, reuse for both q-subtiles
    f32x4 s[2][4];
#pragma unroll
    for (int f = 0; f < 4; ++f) {
      const int row = f * 16 + rr;
      const int swzb = (row & 7) << 4;
      bf16x8 k0 = *(const bf16x8*)((const char*)&sK[cur][row * 64] + ((g * 16) ^ swzb));
      bf16x8 k1 = *(const bf16x8*)((const char*)&sK[cur][row * 64] + ((64 + g * 16) ^ swzb));
      __builtin_amdgcn_s_setprio(1);
#pragma unroll
      for (int qm = 0; qm < 2; ++qm) {
        f32x4 z = __builtin_amdgcn_mfma_f32_16x16x32_bf16(aq[qm][0], k0, z0, 0, 0, 0);
        s[qm][f] = __builtin_amdgcn_mfma_f32_16x16x32_bf16(aq[qm][1], k1, z, 0, 0, 0);
      }
      __builtin_amdgcn_s_setprio(0);
    }

    // p = exp2(s); pack 4 f-values (f-minor kappa layout) into one b64 write per row
    unsigned short* P = &sP[wid][0];
#pragma unroll
    for (int qm = 0; qm < 2; ++qm)
#pragma unroll
      for (int r = 0; r < 4; ++r) {
        float p0 = fexp2(s[qm][0][r]);
        float p1 = fexp2(s[qm][1][r]);
        float p2 = fexp2(s[qm][2][r]);
        float p3 = fexp2(s[qm][3][r]);
        unsigned lo, hi;
        asm("v_cvt_pk_bf16_f32 %0, %1, %2" : "=v"(lo) : "v"(p0), "v"(p1));
        asm("v_cvt_pk_bf16_f32 %0, %1, %2" : "=v"(hi) : "v"(p2), "v"(p3));
        uint2 w2; w2.x = lo; w2.y = hi;
        *(uint2*)((char*)P + (qm * 16 + g * 4 + r) * 144 + rr * 8) = w2;
      }

    // tw fragments for denominator (kappa-ordered, matches P/V slot order)
    bf16x8 tw0 = *(const bf16x8*)&twb[kt * 64 + g * 8];
    bf16x8 tw1 = *(const bf16x8*)&twb[kt * 64 + 32 + g * 8];

    // PV + denominator: V frags reused across both q-subtiles
#pragma unroll
    for (int kk = 0; kk < 2; ++kk) {
      bf16x8 pa[2];
#pragma unroll
      for (int qm = 0; qm < 2; ++qm)
        pa[qm] = *(const bf16x8*)&P[(qm * 16 + rr) * 72 + kk * 32 + g * 8];
      __builtin_amdgcn_s_setprio(1);
#pragma unroll
      for (int n = 0; n < 4; ++n) {
        const int vrow = n * 16 + rr;
        const int cb = (kk * 64 + g * 16) ^ ((vrow & 7) << 4);
        bf16x8 bv = *(const bf16x8*)((const char*)&sV[cur][vrow * 64] + cb);
#pragma unroll
        for (int qm = 0; qm < 2; ++qm)
          acc[qm][n] = __builtin_amdgcn_mfma_f32_16x16x32_bf16(pa[qm], bv, acc[qm][n], 0, 0, 0);
      }
#pragma unroll
      for (int qm = 0; qm < 2; ++qm)
        acc[qm][4] = __builtin_amdgcn_mfma_f32_16x16x32_bf16(pa[qm], kk ? tw1 : tw0, acc[qm][4], 0, 0, 0);
      __builtin_amdgcn_s_setprio(0);
    }
    cur ^= 1;
  }

  unsigned short* Ob = O + ((size_t)b * S + qt * 128 + wid * 32) * DM + h * DK;
#pragma unroll
  for (int qm = 0; qm < 2; ++qm)
#pragma unroll
    for (int n = 0; n < 4; ++n)
#pragma unroll
      for (int r = 0; r < 4; ++r) {
        const int q = qm * 16 + g * 4 + r;
        const int d = n * 16 + rr;
        Ob[(size_t)q * DM + d] = f2bf(acc[qm][n][r] / acc[qm][4][r]);
      }
}

// ---------------- launch ----------------
extern "C" void kernel_launch(void* const* d_in, const int* in_sizes, int n_in,
                              void* d_out, int out_size, void* d_ws, size_t ws_size,
                              hipStream_t stream) {
  const float* x      = (const float*)d_in[0];
  const float* coords = (const float*)d_in[1];
  const float* Wq = (const float*)d_in[2];
  const float* bq = (const float*)d_in[3];
  const float* Wk = (const float*)d_in[4];
  const float* bk = (const float*)d_in[5];
  const float* Wv = (const float*)d_in[6];
  const float* bv = (const float*)d_in[7];
  const float* Wo = (const float*)d_in[8];
  const float* bo = (const float*)d_in[9];

  const int S = in_sizes[1];
  const int B = in_sizes[0] / (S * DM);
  const int M = B * S;
  const float QS = 0.18033688011112042f;   // log2(e)/8

  char* w = (char*)d_ws;
  size_t off = 0;
  unsigned short* xb   = (unsigned short*)(w + off); off += (size_t)M * DM * 2;
  unsigned short* Wcat = (unsigned short*)(w + off); off += (size_t)3 * DM * DM * 2;
  unsigned short* Wob  = (unsigned short*)(w + off); off += (size_t)DM * DM * 2;
  unsigned short* QKVb = (unsigned short*)(w + off); off += (size_t)M * QLD * 2;
  unsigned short* Vtb  = (unsigned short*)(w + off); off += (size_t)M * DM * 2;
  float* tw  = (float*)(w + off); off += (size_t)S * 4;
  unsigned short* twb = (unsigned short*)(w + off); off += (size_t)S * 2;
  float* bcat = (float*)(w + off); off += (size_t)3 * DM * 4;
  unsigned short* Ob = xb;   // alias: xb dead after QKV gemm
  (void)ws_size; (void)n_in; (void)out_size;

  // fused prep (x conv, 4 weight convs, bias cat, tw) — one launch
  {
    int nx = M * DM / 4, nw = DM * DM / 4;
    int total = nx + 4 * nw;
    int tail = 3 * DM + S;
    int gridp = total / 256 + (tail + 255) / 256;
    k_prep<<<gridp, 256, 0, stream>>>(x, Wq, Wk, Wv, Wo, bq, bk, bv, coords,
                                      xb, Wcat, Wob, bcat, tw, twb, M, S, QS);
  }

  // fused QKV projection: [M,1024] x [3072,1024]^T -> [M,3072]
  gemm_bt<0><<<(M / BM) * (3 * DM / BN), 256, 0, stream>>>(xb, Wcat, bcat, QKVb, M, 3 * DM, DM, QLD);

  // V transpose (+ tw prescale, kappa permute) + attention
  k_transpose<<<B * NHEAD * (S / 64), 256, 0, stream>>>(QKVb + 2 * DM, tw, Vtb, S, QLD);
  k_attn<<<B * NHEAD * (S / 128), 256, 0, stream>>>(QKVb, Vtb, twb, Ob, S);

  // output projection (f32 out)
  gemm_bt<1><<<(M / BM) * (DM / BN), 256, 0, stream>>>(Ob, Wob, bo, d_out, M, DM, DM, DM);
}

// Round 5
// 136.566 us; speedup vs baseline: 2.0335x; 1.0193x over previous
//
#include <hip/hip_runtime.h>

#define DM 1024
#define NHEAD 16
#define DK 64
#define QLD 3072   // fused QKV row stride

typedef short bf16x8 __attribute__((ext_vector_type(8)));
typedef float f32x4 __attribute__((ext_vector_type(4)));

__device__ __forceinline__ unsigned short f2bf(float f) {
  union { float f; unsigned u; } v; v.f = f;
  return (unsigned short)((v.u + 0x7fffu + ((v.u >> 16) & 1u)) >> 16);
}
__device__ __forceinline__ float bf2f(unsigned short h) {
  union { unsigned u; float f; } v; v.u = ((unsigned)h) << 16; return v.f;
}
__device__ __forceinline__ float fexp2(float x) {   // bare v_exp_f32: args bounded, no fixup needed
  float r; asm("v_exp_f32 %0, %1" : "=v"(r) : "v"(x)); return r;
}

__device__ __forceinline__ void gld16(const void* g, void* l) {
  __builtin_amdgcn_global_load_lds((const __attribute__((address_space(1))) void*)g,
                                   (__attribute__((address_space(3))) void*)l, 16, 0, 0);
}

// kappa: key = K(slot) within each 64-tile; bijective. Matches swapped-QK register layout.
__device__ __forceinline__ int kappa(int p) {
  return (p & 32) + (((p & 7) >> 2) << 4) + (((p >> 3) & 3) << 2) + (p & 3);
}

// ---------------- fused prep: x conv + 4 weight convs + bias cat + tw ----------------
__global__ void k_prep(const float* __restrict__ x, const float* __restrict__ Wq,
                       const float* __restrict__ Wk, const float* __restrict__ Wv,
                       const float* __restrict__ Wo, const float* __restrict__ bq,
                       const float* __restrict__ bk, const float* __restrict__ bv,
                       const float* __restrict__ coords,
                       unsigned short* __restrict__ xb, unsigned short* __restrict__ Wcat,
                       unsigned short* __restrict__ Wob, float* __restrict__ bcat,
                       float* __restrict__ tw, unsigned short* __restrict__ twb,
                       int M, int S, float QS) {
  const int nx = M * DM / 4;       // x float4 count
  const int nw = DM * DM / 4;      // per-weight float4 count
  const int total = nx + 4 * nw;
  int gid = blockIdx.x * 256 + threadIdx.x;

  auto conv4 = [&](const float* src, unsigned short* dst, int idx, float sc) {
    float4 v = *(const float4*)(src + idx * 4);
    ushort4 o;
    o.x = f2bf(v.x * sc); o.y = f2bf(v.y * sc);
    o.z = f2bf(v.z * sc); o.w = f2bf(v.w * sc);
    *(ushort4*)(dst + idx * 4) = o;
  };

  if (gid < nx) { conv4(x, xb, gid, 1.0f); return; }
  if (gid < nx + nw) { conv4(Wq, Wcat, gid - nx, QS); return; }
  if (gid < nx + 2 * nw) { conv4(Wk, Wcat + DM * DM, gid - nx - nw, 1.0f); return; }
  if (gid < nx + 3 * nw) { conv4(Wv, Wcat + 2 * DM * DM, gid - nx - 2 * nw, 1.0f); return; }
  if (gid < total) { conv4(Wo, Wob, gid - nx - 3 * nw, 1.0f); return; }

  int r = gid - total;
  if (r < 3 * DM) {
    float v = (r < DM) ? bq[r] * QS : (r < 2 * DM ? bk[r - DM] : bv[r - 2 * DM]);
    bcat[r] = v;
    return;
  }
  r -= 3 * DM;
  if (r < S) {
    auto twval = [&](int k) {
      float a = (k > 0)     ? fabsf(coords[k] - coords[k - 1]) : 0.f;
      float b = (k < S - 1) ? fabsf(coords[k + 1] - coords[k]) : 0.f;
      return 0.5f * (a + b);
    };
    tw[r] = twval(r);
    int key = (r & ~63) + kappa(r & 63);
    twb[r] = f2bf(twval(key));
  }
}

// ---------------- GEMM: C[M,N] = A[M,K] * B[N,K]^T + bias ----------------
#define BM 128
#define BN 128
#define BKK 64

template<int OUTF32>
__global__ __launch_bounds__(256)
void gemm_bt(const unsigned short* __restrict__ A, const unsigned short* __restrict__ B,
             const float* __restrict__ bias, void* __restrict__ C,
             int M, int N, int K, int ldc) {
  __shared__ __align__(16) unsigned short sA[2][BM * BKK];
  __shared__ __align__(16) unsigned short sB[2][BN * BKK];
  const int tid = threadIdx.x;
  const int lane = tid & 63;
  const int wid = tid >> 6;
  const int rr = lane & 15, g = lane >> 4;
  const int nbn = N / BN;
  const int cpx = gridDim.x >> 3;
  const int bid = ((gridDim.x & 7) == 0) ? (blockIdx.x & 7) * cpx + (blockIdx.x >> 3)
                                         : blockIdx.x;
  const int bm = bid / nbn, bn = bid % nbn;
  const int wr = wid >> 1, wc = wid & 1;
  const int nkt = K / BKK;

  const unsigned short* Abase = A + (size_t)bm * BM * K;
  const unsigned short* Bbase = B + (size_t)bn * BN * K;

  auto stage = [&](int buf, int kt) {
#pragma unroll
    for (int j = 0; j < 4; ++j) {
      int o = j * 256 + tid;
      int row = o >> 3;
      int ce = (o & 7) * 8;
      gld16(Abase + (size_t)row * K + kt * BKK + ce, &sA[buf][o * 8]);
      gld16(Bbase + (size_t)row * K + kt * BKK + ce, &sB[buf][o * 8]);
    }
  };

  f32x4 acc[4][4] = {};
  stage(0, 0);
  int cur = 0;
  for (int kt = 0; kt < nkt; ++kt) {
    __syncthreads();
    if (kt + 1 < nkt) stage(cur ^ 1, kt + 1);
    const unsigned short* a0 = &sA[cur][(wr * 64) * BKK];
    const unsigned short* b0 = &sB[cur][(wc * 64) * BKK];
#pragma unroll
    for (int kk = 0; kk < 2; ++kk) {
      const int co = kk * 32 + g * 8;
      bf16x8 af[4], bfr[4];
#pragma unroll
      for (int m = 0; m < 4; ++m)
        af[m] = *(const bf16x8*)&a0[(m * 16 + rr) * BKK + co];
#pragma unroll
      for (int n = 0; n < 4; ++n)
        bfr[n] = *(const bf16x8*)&b0[(n * 16 + rr) * BKK + co];
      __builtin_amdgcn_s_setprio(1);
#pragma unroll
      for (int m = 0; m < 4; ++m)
#pragma unroll
        for (int n = 0; n < 4; ++n)
          acc[m][n] = __builtin_amdgcn_mfma_f32_16x16x32_bf16(af[m], bfr[n], acc[m][n], 0, 0, 0);
      __builtin_amdgcn_s_setprio(0);
    }
    cur ^= 1;
  }

  const int crow0 = bm * BM + wr * 64;
  const int ccol0 = bn * BN + wc * 64;
#pragma unroll
  for (int n = 0; n < 4; ++n) {
    const int col = ccol0 + n * 16 + rr;
    const float bn_ = bias ? bias[col] : 0.f;
#pragma unroll
    for (int m = 0; m < 4; ++m)
#pragma unroll
      for (int r = 0; r < 4; ++r) {
        const int row = crow0 + m * 16 + g * 4 + r;
        float v = acc[m][n][r] + bn_;
        if (OUTF32) ((float*)C)[(size_t)row * ldc + col] = v;
        else ((unsigned short*)C)[(size_t)row * ldc + col] = f2bf(v);
      }
  }
}

// ---------------- V transpose + tw prescale + kappa permute ----------------
__global__ __launch_bounds__(256)
void k_transpose(const unsigned short* __restrict__ V, const float* __restrict__ tw,
                 unsigned short* __restrict__ Vt, int S, int ld) {
  __shared__ __align__(16) unsigned short t[64][72];
  __shared__ float tws[64];
  const int nst = S / 64;
  int st = blockIdx.x % nst;
  int bh = blockIdx.x / nst;
  int h = bh & (NHEAD - 1), b = bh / NHEAD;
  const unsigned short* src = V + ((size_t)b * S + st * 64) * ld + h * DK;
  unsigned short* dst = Vt + (size_t)bh * DK * S + st * 64;
  int tid = threadIdx.x;
  if (tid < 64) tws[tid] = tw[st * 64 + tid];
#pragma unroll
  for (int i = 0; i < 2; ++i) {
    int r = i * 32 + (tid >> 3);
    int c = (tid & 7) * 8;
    *(uint4*)&t[r][c] = *(const uint4*)&src[(size_t)r * ld + c];
  }
  __syncthreads();
#pragma unroll
  for (int i = 0; i < 2; ++i) {
    int d = i * 32 + (tid >> 3);
    int p0 = (tid & 7) * 8;
    unsigned short tmp[8];
#pragma unroll
    for (int j = 0; j < 8; ++j) {
      int kl = kappa(p0 + j);    // slot -> key within 64-tile
      tmp[j] = f2bf(bf2f(t[kl][d]) * tws[kl]);
    }
    *(uint4*)&dst[(size_t)d * S + p0] = *(const uint4*)&tmp[0];
  }
}

// ---------------- attention: swapped QK^T, P in registers, denom via tw-MFMA ----------------
// 4 waves x 32 q-rows = 128 q-rows per block; KVBLK=64.
__global__ __launch_bounds__(256)
void k_attn(const unsigned short* __restrict__ QKV, const unsigned short* __restrict__ Vt,
            const unsigned short* __restrict__ twb, unsigned short* __restrict__ O, int S) {
  __shared__ __align__(16) unsigned short sK[2][64 * 64];
  __shared__ __align__(16) unsigned short sV[2][64 * 64];
  const int tid = threadIdx.x, lane = tid & 63, wid = tid >> 6;
  const int rr = lane & 15, g = lane >> 4;
  const int nqt = S / 128;
  const int cpx = gridDim.x >> 3;
  const int swz = (blockIdx.x & 7) * cpx + (blockIdx.x >> 3);
  const int qt = swz % nqt;
  const int bh = swz / nqt;
  const int h = bh & (NHEAD - 1), b = bh / NHEAD;

  const unsigned short* Qbase = QKV + ((size_t)b * S + qt * 128 + wid * 32) * QLD + h * DK;
  const unsigned short* Kbase = QKV + (size_t)b * S * QLD + DM + h * DK;
  const unsigned short* Vbase = Vt + (size_t)bh * DK * S;

  bf16x8 aq[2][2];
#pragma unroll
  for (int qm = 0; qm < 2; ++qm) {
    aq[qm][0] = *(const bf16x8*)&Qbase[(size_t)(qm * 16 + rr) * QLD + g * 8];
    aq[qm][1] = *(const bf16x8*)&Qbase[(size_t)(qm * 16 + rr) * QLD + 32 + g * 8];
  }

  f32x4 acc[2][5] = {};
  const f32x4 z0 = {};

  auto stage = [&](int buf, int kt) {
#pragma unroll
    for (int j = 0; j < 2; ++j) {
      int o = j * 256 + tid;
      int row = o >> 3;
      int cb = ((o & 7) * 16) ^ ((row & 7) << 4);
      gld16((const char*)(Kbase + (size_t)(kt * 64 + row) * QLD) + cb, &sK[buf][o * 8]);
      gld16((const char*)(Vbase + (size_t)row * S + kt * 64) + cb, &sV[buf][o * 8]);
    }
  };

  stage(0, 0);
  int cur = 0;
  const int nkt = S / 64;
  for (int kt = 0; kt < nkt; ++kt) {
    __syncthreads();
    if (kt + 1 < nkt) stage(cur ^ 1, kt + 1);

    // swapped scores: s[qm][f] = P[key=16f+4g+r][q=qm*16+rr]
    f32x4 s[2][4];
#pragma unroll
    for (int f = 0; f < 4; ++f) {
      const int row = f * 16 + rr;
      const int swzb = (row & 7) << 4;
      bf16x8 kA0 = *(const bf16x8*)((const char*)&sK[cur][row * 64] + ((g * 16) ^ swzb));
      bf16x8 kA1 = *(const bf16x8*)((const char*)&sK[cur][row * 64] + ((64 + g * 16) ^ swzb));
      __builtin_amdgcn_s_setprio(1);
#pragma unroll
      for (int qm = 0; qm < 2; ++qm) {
        f32x4 z = __builtin_amdgcn_mfma_f32_16x16x32_bf16(kA0, aq[qm][0], z0, 0, 0, 0);
        s[qm][f] = __builtin_amdgcn_mfma_f32_16x16x32_bf16(kA1, aq[qm][1], z, 0, 0, 0);
      }
      __builtin_amdgcn_s_setprio(0);
    }

    // p = exp2(s) in place (lane-local)
#pragma unroll
    for (int qm = 0; qm < 2; ++qm)
#pragma unroll
      for (int f = 0; f < 4; ++f)
#pragma unroll
        for (int r = 0; r < 4; ++r)
          s[qm][f][r] = fexp2(s[qm][f][r]);

    // pack P into A-frags entirely in registers: slot kk*32+g*8+j -> (f=2kk+(j>>2), r=j&3)
    bf16x8 pa[2][2];
#pragma unroll
    for (int qm = 0; qm < 2; ++qm)
#pragma unroll
      for (int kk = 0; kk < 2; ++kk) {
        union { bf16x8 v; unsigned u[4]; } pk;
        asm("v_cvt_pk_bf16_f32 %0, %1, %2" : "=v"(pk.u[0]) : "v"(s[qm][2*kk][0]),   "v"(s[qm][2*kk][1]));
        asm("v_cvt_pk_bf16_f32 %0, %1, %2" : "=v"(pk.u[1]) : "v"(s[qm][2*kk][2]),   "v"(s[qm][2*kk][3]));
        asm("v_cvt_pk_bf16_f32 %0, %1, %2" : "=v"(pk.u[2]) : "v"(s[qm][2*kk+1][0]), "v"(s[qm][2*kk+1][1]));
        asm("v_cvt_pk_bf16_f32 %0, %1, %2" : "=v"(pk.u[3]) : "v"(s[qm][2*kk+1][2]), "v"(s[qm][2*kk+1][3]));
        pa[qm][kk] = pk.v;
      }

    // tw fragments for denominator (kappa-ordered, matches V slot order)
    bf16x8 tw0 = *(const bf16x8*)&twb[kt * 64 + g * 8];
    bf16x8 tw1 = *(const bf16x8*)&twb[kt * 64 + 32 + g * 8];

    // PV + denominator: V frags reused across both q-subtiles
#pragma unroll
    for (int kk = 0; kk < 2; ++kk) {
      __builtin_amdgcn_s_setprio(1);
#pragma unroll
      for (int n = 0; n < 4; ++n) {
        const int vrow = n * 16 + rr;
        const int cb = (kk * 64 + g * 16) ^ ((vrow & 7) << 4);
        bf16x8 bv = *(const bf16x8*)((const char*)&sV[cur][vrow * 64] + cb);
#pragma unroll
        for (int qm = 0; qm < 2; ++qm)
          acc[qm][n] = __builtin_amdgcn_mfma_f32_16x16x32_bf16(pa[qm][kk], bv, acc[qm][n], 0, 0, 0);
      }
#pragma unroll
      for (int qm = 0; qm < 2; ++qm)
        acc[qm][4] = __builtin_amdgcn_mfma_f32_16x16x32_bf16(pa[qm][kk], kk ? tw1 : tw0, acc[qm][4], 0, 0, 0);
      __builtin_amdgcn_s_setprio(0);
    }
    cur ^= 1;
  }

  unsigned short* Ob = O + ((size_t)b * S + qt * 128 + wid * 32) * DM + h * DK;
#pragma unroll
  for (int qm = 0; qm < 2; ++qm)
#pragma unroll
    for (int n = 0; n < 4; ++n)
#pragma unroll
      for (int r = 0; r < 4; ++r) {
        const int q = qm * 16 + g * 4 + r;
        const int d = n * 16 + rr;
        Ob[(size_t)q * DM + d] = f2bf(acc[qm][n][r] / acc[qm][4][r]);
      }
}

// ---------------- launch ----------------
extern "C" void kernel_launch(void* const* d_in, const int* in_sizes, int n_in,
                              void* d_out, int out_size, void* d_ws, size_t ws_size,
                              hipStream_t stream) {
  const float* x      = (const float*)d_in[0];
  const float* coords = (const float*)d_in[1];
  const float* Wq = (const float*)d_in[2];
  const float* bq = (const float*)d_in[3];
  const float* Wk = (const float*)d_in[4];
  const float* bk = (const float*)d_in[5];
  const float* Wv = (const float*)d_in[6];
  const float* bv = (const float*)d_in[7];
  const float* Wo = (const float*)d_in[8];
  const float* bo = (const float*)d_in[9];

  const int S = in_sizes[1];
  const int B = in_sizes[0] / (S * DM);
  const int M = B * S;
  const float QS = 0.18033688011112042f;   // log2(e)/8

  char* w = (char*)d_ws;
  size_t off = 0;
  unsigned short* xb   = (unsigned short*)(w + off); off += (size_t)M * DM * 2;
  unsigned short* Wcat = (unsigned short*)(w + off); off += (size_t)3 * DM * DM * 2;
  unsigned short* Wob  = (unsigned short*)(w + off); off += (size_t)DM * DM * 2;
  unsigned short* QKVb = (unsigned short*)(w + off); off += (size_t)M * QLD * 2;
  unsigned short* Vtb  = (unsigned short*)(w + off); off += (size_t)M * DM * 2;
  float* tw  = (float*)(w + off); off += (size_t)S * 4;
  unsigned short* twb = (unsigned short*)(w + off); off += (size_t)S * 2;
  float* bcat = (float*)(w + off); off += (size_t)3 * DM * 4;
  unsigned short* Ob = xb;   // alias: xb dead after QKV gemm
  (void)ws_size; (void)n_in; (void)out_size;

  // fused prep (x conv, 4 weight convs, bias cat, tw) — one launch
  {
    int nx = M * DM / 4, nw = DM * DM / 4;
    int total = nx + 4 * nw;
    int tail = 3 * DM + S;
    int gridp = total / 256 + (tail + 255) / 256;
    k_prep<<<gridp, 256, 0, stream>>>(x, Wq, Wk, Wv, Wo, bq, bk, bv, coords,
                                      xb, Wcat, Wob, bcat, tw, twb, M, S, QS);
  }

  // fused QKV projection: [M,1024] x [3072,1024]^T -> [M,3072]
  gemm_bt<0><<<(M / BM) * (3 * DM / BN), 256, 0, stream>>>(xb, Wcat, bcat, QKVb, M, 3 * DM, DM, QLD);

  // V transpose (+ tw prescale, kappa permute) + attention
  k_transpose<<<B * NHEAD * (S / 64), 256, 0, stream>>>(QKVb + 2 * DM, tw, Vtb, S, QLD);
  k_attn<<<B * NHEAD * (S / 128), 256, 0, stream>>>(QKVb, Vtb, twb, Ob, S);

  // output projection (f32 out)
  gemm_bt<1><<<(M / BM) * (DM / BN), 256, 0, stream>>>(Ob, Wob, bo, d_out, M, DM, DM, DM);
}

// Round 6
// 124.056 us; speedup vs baseline: 2.2386x; 1.1008x over previous
//
#include <hip/hip_runtime.h>

#define DM 1024
#define NHEAD 16
#define DK 64
#define QLD 3072   // fused QKV row stride

typedef short bf16x8 __attribute__((ext_vector_type(8)));
typedef float f32x4 __attribute__((ext_vector_type(4)));

__device__ __forceinline__ unsigned short f2bf(float f) {
  union { float f; unsigned u; } v; v.f = f;
  return (unsigned short)((v.u + 0x7fffu + ((v.u >> 16) & 1u)) >> 16);
}
__device__ __forceinline__ float bf2f(unsigned short h) {
  union { unsigned u; float f; } v; v.u = ((unsigned)h) << 16; return v.f;
}
__device__ __forceinline__ float fexp2(float x) {   // bare v_exp_f32: args bounded, no fixup needed
  float r; asm("v_exp_f32 %0, %1" : "=v"(r) : "v"(x)); return r;
}

__device__ __forceinline__ void gld16(const void* g, void* l) {
  __builtin_amdgcn_global_load_lds((const __attribute__((address_space(1))) void*)g,
                                   (__attribute__((address_space(3))) void*)l, 16, 0, 0);
}

// kappa: key = K(slot) within each 64-tile; bijective. Matches swapped-QK register layout.
__device__ __forceinline__ int kappa(int p) {
  return (p & 32) + (((p & 7) >> 2) << 4) + (((p >> 3) & 3) << 2) + (p & 3);
}

// ---------------- fused prep: x conv + 4 weight convs + bias cat + tw ----------------
__global__ void k_prep(const float* __restrict__ x, const float* __restrict__ Wq,
                       const float* __restrict__ Wk, const float* __restrict__ Wv,
                       const float* __restrict__ Wo, const float* __restrict__ bq,
                       const float* __restrict__ bk, const float* __restrict__ bv,
                       const float* __restrict__ coords,
                       unsigned short* __restrict__ xb, unsigned short* __restrict__ Wcat,
                       unsigned short* __restrict__ Wob, float* __restrict__ bcat,
                       float* __restrict__ tw, unsigned short* __restrict__ twb,
                       int M, int S, float QS) {
  const int nx = M * DM / 4;       // x float4 count
  const int nw = DM * DM / 4;      // per-weight float4 count
  const int total = nx + 4 * nw;
  int gid = blockIdx.x * 256 + threadIdx.x;

  auto conv4 = [&](const float* src, unsigned short* dst, int idx, float sc) {
    float4 v = *(const float4*)(src + idx * 4);
    ushort4 o;
    o.x = f2bf(v.x * sc); o.y = f2bf(v.y * sc);
    o.z = f2bf(v.z * sc); o.w = f2bf(v.w * sc);
    *(ushort4*)(dst + idx * 4) = o;
  };

  if (gid < nx) { conv4(x, xb, gid, 1.0f); return; }
  if (gid < nx + nw) { conv4(Wq, Wcat, gid - nx, QS); return; }
  if (gid < nx + 2 * nw) { conv4(Wk, Wcat + DM * DM, gid - nx - nw, 1.0f); return; }
  if (gid < nx + 3 * nw) { conv4(Wv, Wcat + 2 * DM * DM, gid - nx - 2 * nw, 1.0f); return; }
  if (gid < total) { conv4(Wo, Wob, gid - nx - 3 * nw, 1.0f); return; }

  int r = gid - total;
  if (r < 3 * DM) {
    float v = (r < DM) ? bq[r] * QS : (r < 2 * DM ? bk[r - DM] : bv[r - 2 * DM]);
    bcat[r] = v;
    return;
  }
  r -= 3 * DM;
  if (r < S) {
    auto twval = [&](int k) {
      float a = (k > 0)     ? fabsf(coords[k] - coords[k - 1]) : 0.f;
      float b = (k < S - 1) ? fabsf(coords[k + 1] - coords[k]) : 0.f;
      return 0.5f * (a + b);
    };
    tw[r] = twval(r);
    int key = (r & ~63) + kappa(r & 63);
    twb[r] = f2bf(twval(key));
  }
}

// ---------------- GEMM: C[M,N] = A[M,K] * B[N,K]^T + bias ----------------
// T2 XOR-swizzled LDS (pre-swizzled gld16 source + swizzled frag reads).
#define BM 128
#define BN 128
#define BKK 64

template<int OUTF32>
__global__ __launch_bounds__(256)
void gemm_bt(const unsigned short* __restrict__ A, const unsigned short* __restrict__ B,
             const float* __restrict__ bias, void* __restrict__ C,
             int M, int N, int K, int ldc) {
  __shared__ __align__(16) unsigned short sA[2][BM * BKK];
  __shared__ __align__(16) unsigned short sB[2][BN * BKK];
  const int tid = threadIdx.x;
  const int lane = tid & 63;
  const int wid = tid >> 6;
  const int rr = lane & 15, g = lane >> 4;
  const int nbn = N / BN;
  const int cpx = gridDim.x >> 3;
  const int bid = ((gridDim.x & 7) == 0) ? (blockIdx.x & 7) * cpx + (blockIdx.x >> 3)
                                         : blockIdx.x;
  const int bm = bid / nbn, bn = bid % nbn;
  const int wr = wid >> 1, wc = wid & 1;
  const int nkt = K / BKK;

  const unsigned short* Abase = A + (size_t)bm * BM * K;
  const unsigned short* Bbase = B + (size_t)bn * BN * K;

  auto stage = [&](int buf, int kt) {
#pragma unroll
    for (int j = 0; j < 4; ++j) {
      int o = j * 256 + tid;
      int row = o >> 3;
      int cb = ((o & 7) * 16) ^ ((row & 7) << 4);   // inverse-swizzled source byte col
      gld16((const char*)(Abase + (size_t)row * K + kt * BKK) + cb, &sA[buf][o * 8]);
      gld16((const char*)(Bbase + (size_t)row * K + kt * BKK) + cb, &sB[buf][o * 8]);
    }
  };

  f32x4 acc[4][4] = {};
  stage(0, 0);
  int cur = 0;
  const int sw = (rr & 7) << 4;
  for (int kt = 0; kt < nkt; ++kt) {
    __syncthreads();
    if (kt + 1 < nkt) stage(cur ^ 1, kt + 1);
    const char* a0 = (const char*)&sA[cur][(wr * 64) * BKK];
    const char* b0 = (const char*)&sB[cur][(wc * 64) * BKK];
#pragma unroll
    for (int kk = 0; kk < 2; ++kk) {
      const int co = (kk * 64 + g * 16);
      bf16x8 af[4], bfr[4];
#pragma unroll
      for (int m = 0; m < 4; ++m)
        af[m] = *(const bf16x8*)(a0 + (m * 16 + rr) * 128 + (co ^ sw));
#pragma unroll
      for (int n = 0; n < 4; ++n)
        bfr[n] = *(const bf16x8*)(b0 + (n * 16 + rr) * 128 + (co ^ sw));
      __builtin_amdgcn_s_setprio(1);
#pragma unroll
      for (int m = 0; m < 4; ++m)
#pragma unroll
        for (int n = 0; n < 4; ++n)
          acc[m][n] = __builtin_amdgcn_mfma_f32_16x16x32_bf16(af[m], bfr[n], acc[m][n], 0, 0, 0);
      __builtin_amdgcn_s_setprio(0);
    }
    cur ^= 1;
  }

  const int crow0 = bm * BM + wr * 64;
  const int ccol0 = bn * BN + wc * 64;
#pragma unroll
  for (int n = 0; n < 4; ++n) {
    const int col = ccol0 + n * 16 + rr;
    const float bn_ = bias ? bias[col] : 0.f;
#pragma unroll
    for (int m = 0; m < 4; ++m)
#pragma unroll
      for (int r = 0; r < 4; ++r) {
        const int row = crow0 + m * 16 + g * 4 + r;
        float v = acc[m][n][r] + bn_;
        if (OUTF32) ((float*)C)[(size_t)row * ldc + col] = v;
        else ((unsigned short*)C)[(size_t)row * ldc + col] = f2bf(v);
      }
  }
}

// ---------------- V transpose + tw prescale + kappa permute ----------------
__global__ __launch_bounds__(256)
void k_transpose(const unsigned short* __restrict__ V, const float* __restrict__ tw,
                 unsigned short* __restrict__ Vt, int S, int ld) {
  __shared__ __align__(16) unsigned short t[64][72];
  __shared__ float tws[64];
  const int nst = S / 64;
  int st = blockIdx.x % nst;
  int bh = blockIdx.x / nst;
  int h = bh & (NHEAD - 1), b = bh / NHEAD;
  const unsigned short* src = V + ((size_t)b * S + st * 64) * ld + h * DK;
  unsigned short* dst = Vt + (size_t)bh * DK * S + st * 64;
  int tid = threadIdx.x;
  if (tid < 64) tws[tid] = tw[st * 64 + tid];
#pragma unroll
  for (int i = 0; i < 2; ++i) {
    int r = i * 32 + (tid >> 3);
    int c = (tid & 7) * 8;
    *(uint4*)&t[r][c] = *(const uint4*)&src[(size_t)r * ld + c];
  }
  __syncthreads();
#pragma unroll
  for (int i = 0; i < 2; ++i) {
    int d = i * 32 + (tid >> 3);
    int p0 = (tid & 7) * 8;
    unsigned short tmp[8];
#pragma unroll
    for (int j = 0; j < 8; ++j) {
      int kl = kappa(p0 + j);    // slot -> key within 64-tile
      tmp[j] = f2bf(bf2f(t[kl][d]) * tws[kl]);
    }
    *(uint4*)&dst[(size_t)d * S + p0] = *(const uint4*)&tmp[0];
  }
}

// ---------------- attention: swapped QK^T, P in registers, denom via tw-MFMA ----------------
// 4 waves x 32 q-rows = 128 q-rows per block; KVBLK=64.
__global__ __launch_bounds__(256)
void k_attn(const unsigned short* __restrict__ QKV, const unsigned short* __restrict__ Vt,
            const unsigned short* __restrict__ twb, unsigned short* __restrict__ O, int S) {
  __shared__ __align__(16) unsigned short sK[2][64 * 64];
  __shared__ __align__(16) unsigned short sV[2][64 * 64];
  const int tid = threadIdx.x, lane = tid & 63, wid = tid >> 6;
  const int rr = lane & 15, g = lane >> 4;
  const int nqt = S / 128;
  const int cpx = gridDim.x >> 3;
  const int swz = (blockIdx.x & 7) * cpx + (blockIdx.x >> 3);
  const int qt = swz % nqt;
  const int bh = swz / nqt;
  const int h = bh & (NHEAD - 1), b = bh / NHEAD;

  const unsigned short* Qbase = QKV + ((size_t)b * S + qt * 128 + wid * 32) * QLD + h * DK;
  const unsigned short* Kbase = QKV + (size_t)b * S * QLD + DM + h * DK;
  const unsigned short* Vbase = Vt + (size_t)bh * DK * S;

  bf16x8 aq[2][2];
#pragma unroll
  for (int qm = 0; qm < 2; ++qm) {
    aq[qm][0] = *(const bf16x8*)&Qbase[(size_t)(qm * 16 + rr) * QLD + g * 8];
    aq[qm][1] = *(const bf16x8*)&Qbase[(size_t)(qm * 16 + rr) * QLD + 32 + g * 8];
  }

  f32x4 acc[2][5] = {};
  const f32x4 z0 = {};

  auto stage = [&](int buf, int kt) {
#pragma unroll
    for (int j = 0; j < 2; ++j) {
      int o = j * 256 + tid;
      int row = o >> 3;
      int cb = ((o & 7) * 16) ^ ((row & 7) << 4);
      gld16((const char*)(Kbase + (size_t)(kt * 64 + row) * QLD) + cb, &sK[buf][o * 8]);
      gld16((const char*)(Vbase + (size_t)row * S + kt * 64) + cb, &sV[buf][o * 8]);
    }
  };

  stage(0, 0);
  int cur = 0;
  const int nkt = S / 64;
  for (int kt = 0; kt < nkt; ++kt) {
    __syncthreads();
    if (kt + 1 < nkt) stage(cur ^ 1, kt + 1);

    // swapped scores: s[qm][f] = P[key=16f+4g+r][q=qm*16+rr]
    f32x4 s[2][4];
#pragma unroll
    for (int f = 0; f < 4; ++f) {
      const int row = f * 16 + rr;
      const int swzb = (row & 7) << 4;
      bf16x8 kA0 = *(const bf16x8*)((const char*)&sK[cur][row * 64] + ((g * 16) ^ swzb));
      bf16x8 kA1 = *(const bf16x8*)((const char*)&sK[cur][row * 64] + ((64 + g * 16) ^ swzb));
      __builtin_amdgcn_s_setprio(1);
#pragma unroll
      for (int qm = 0; qm < 2; ++qm) {
        f32x4 z = __builtin_amdgcn_mfma_f32_16x16x32_bf16(kA0, aq[qm][0], z0, 0, 0, 0);
        s[qm][f] = __builtin_amdgcn_mfma_f32_16x16x32_bf16(kA1, aq[qm][1], z, 0, 0, 0);
      }
      __builtin_amdgcn_s_setprio(0);
    }

    // p = exp2(s) in place (lane-local)
#pragma unroll
    for (int qm = 0; qm < 2; ++qm)
#pragma unroll
      for (int f = 0; f < 4; ++f)
#pragma unroll
        for (int r = 0; r < 4; ++r)
          s[qm][f][r] = fexp2(s[qm][f][r]);

    // pack P into A-frags entirely in registers: slot kk*32+g*8+j -> (f=2kk+(j>>2), r=j&3)
    bf16x8 pa[2][2];
#pragma unroll
    for (int qm = 0; qm < 2; ++qm)
#pragma unroll
      for (int kk = 0; kk < 2; ++kk) {
        union { bf16x8 v; unsigned u[4]; } pk;
        asm("v_cvt_pk_bf16_f32 %0, %1, %2" : "=v"(pk.u[0]) : "v"(s[qm][2*kk][0]),   "v"(s[qm][2*kk][1]));
        asm("v_cvt_pk_bf16_f32 %0, %1, %2" : "=v"(pk.u[1]) : "v"(s[qm][2*kk][2]),   "v"(s[qm][2*kk][3]));
        asm("v_cvt_pk_bf16_f32 %0, %1, %2" : "=v"(pk.u[2]) : "v"(s[qm][2*kk+1][0]), "v"(s[qm][2*kk+1][1]));
        asm("v_cvt_pk_bf16_f32 %0, %1, %2" : "=v"(pk.u[3]) : "v"(s[qm][2*kk+1][2]), "v"(s[qm][2*kk+1][3]));
        pa[qm][kk] = pk.v;
      }

    // tw fragments for denominator (kappa-ordered, matches V slot order)
    bf16x8 tw0 = *(const bf16x8*)&twb[kt * 64 + g * 8];
    bf16x8 tw1 = *(const bf16x8*)&twb[kt * 64 + 32 + g * 8];

    // PV + denominator: V frags reused across both q-subtiles
#pragma unroll
    for (int kk = 0; kk < 2; ++kk) {
      __builtin_amdgcn_s_setprio(1);
#pragma unroll
      for (int n = 0; n < 4; ++n) {
        const int vrow = n * 16 + rr;
        const int cb = (kk * 64 + g * 16) ^ ((vrow & 7) << 4);
        bf16x8 bv = *(const bf16x8*)((const char*)&sV[cur][vrow * 64] + cb);
#pragma unroll
        for (int qm = 0; qm < 2; ++qm)
          acc[qm][n] = __builtin_amdgcn_mfma_f32_16x16x32_bf16(pa[qm][kk], bv, acc[qm][n], 0, 0, 0);
      }
#pragma unroll
      for (int qm = 0; qm < 2; ++qm)
        acc[qm][4] = __builtin_amdgcn_mfma_f32_16x16x32_bf16(pa[qm][kk], kk ? tw1 : tw0, acc[qm][4], 0, 0, 0);
      __builtin_amdgcn_s_setprio(0);
    }
    cur ^= 1;
  }

  unsigned short* Ob = O + ((size_t)b * S + qt * 128 + wid * 32) * DM + h * DK;
#pragma unroll
  for (int qm = 0; qm < 2; ++qm)
#pragma unroll
    for (int n = 0; n < 4; ++n)
#pragma unroll
      for (int r = 0; r < 4; ++r) {
        const int q = qm * 16 + g * 4 + r;
        const int d = n * 16 + rr;
        Ob[(size_t)q * DM + d] = f2bf(acc[qm][n][r] / acc[qm][4][r]);
      }
}

// ---------------- launch ----------------
extern "C" void kernel_launch(void* const* d_in, const int* in_sizes, int n_in,
                              void* d_out, int out_size, void* d_ws, size_t ws_size,
                              hipStream_t stream) {
  const float* x      = (const float*)d_in[0];
  const float* coords = (const float*)d_in[1];
  const float* Wq = (const float*)d_in[2];
  const float* bq = (const float*)d_in[3];
  const float* Wk = (const float*)d_in[4];
  const float* bk = (const float*)d_in[5];
  const float* Wv = (const float*)d_in[6];
  const float* bv = (const float*)d_in[7];
  const float* Wo = (const float*)d_in[8];
  const float* bo = (const float*)d_in[9];

  const int S = in_sizes[1];
  const int B = in_sizes[0] / (S * DM);
  const int M = B * S;
  const float QS = 0.18033688011112042f;   // log2(e)/8

  char* w = (char*)d_ws;
  size_t off = 0;
  unsigned short* xb   = (unsigned short*)(w + off); off += (size_t)M * DM * 2;
  unsigned short* Wcat = (unsigned short*)(w + off); off += (size_t)3 * DM * DM * 2;
  unsigned short* Wob  = (unsigned short*)(w + off); off += (size_t)DM * DM * 2;
  unsigned short* QKVb = (unsigned short*)(w + off); off += (size_t)M * QLD * 2;
  unsigned short* Vtb  = (unsigned short*)(w + off); off += (size_t)M * DM * 2;
  float* tw  = (float*)(w + off); off += (size_t)S * 4;
  unsigned short* twb = (unsigned short*)(w + off); off += (size_t)S * 2;
  float* bcat = (float*)(w + off); off += (size_t)3 * DM * 4;
  unsigned short* Ob = xb;   // alias: xb dead after QKV gemm
  (void)ws_size; (void)n_in; (void)out_size;

  // fused prep (x conv, 4 weight convs, bias cat, tw) — one launch
  {
    int nx = M * DM / 4, nw = DM * DM / 4;
    int total = nx + 4 * nw;
    int tail = 3 * DM + S;
    int gridp = total / 256 + (tail + 255) / 256;
    k_prep<<<gridp, 256, 0, stream>>>(x, Wq, Wk, Wv, Wo, bq, bk, bv, coords,
                                      xb, Wcat, Wob, bcat, tw, twb, M, S, QS);
  }

  // fused QKV projection: [M,1024] x [3072,1024]^T -> [M,3072]
  gemm_bt<0><<<(M / BM) * (3 * DM / BN), 256, 0, stream>>>(xb, Wcat, bcat, QKVb, M, 3 * DM, DM, QLD);

  // V transpose (+ tw prescale, kappa permute) + attention
  k_transpose<<<B * NHEAD * (S / 64), 256, 0, stream>>>(QKVb + 2 * DM, tw, Vtb, S, QLD);
  k_attn<<<B * NHEAD * (S / 128), 256, 0, stream>>>(QKVb, Vtb, twb, Ob, S);

  // output projection (f32 out)
  gemm_bt<1><<<(M / BM) * (DM / BN), 256, 0, stream>>>(Ob, Wob, bo, d_out, M, DM, DM, DM);
}